// Round 4
// baseline (47251.608 us; speedup 1.0000x reference)
//
#include <hip/hip_runtime.h>
#include <hip/hip_bf16.h>
#include <hip/hip_cooperative_groups.h>

namespace cg = cooperative_groups;

// CharRNN: embed -> 4x (LayerNorm-LSTM over T=128) -> projection to vocab.
// Round 3: single cooperative kernel for all 4 layers. W-hi slice pinned in
// LDS (128 KB/block, XOR-swizzled), W-lo streamed from L2. zx/xgemm removed:
// phase A computes full [x,h]@W (K=2048). x-part of step t+1 overlapped with
// the gate phase via dedicated row-blocks (grid = 128 col + 32 row blocks).

typedef __bf16 bf16x8 __attribute__((ext_vector_type(8)));
typedef __bf16 bf16x4 __attribute__((ext_vector_type(4)));
typedef float  f32x4  __attribute__((ext_vector_type(4)));

#define VOCAB 32000
#define BATCH 32
#define SEQ   128
#define RNN   1024
#define NLAY  4
#define NCOLB 128
#define NROWB 32
#define GBLK  (NCOLB + NROWB)

__device__ __forceinline__ float sigm(float x) { return 1.f / (1.f + __expf(-x)); }

// ---------------------------------------------------------------------------
// W [L][2048][4096] f32 -> Wt [L][2 planes (hi,lo)][4096][2048] bf16,
// transposed to [n][k]. k 0..1023 = x-part (Wx), k 1024..2047 = h-part (Wh).
__global__ __launch_bounds__(256) void k_cvt_w(const float* __restrict__ W,
                                               __bf16* __restrict__ Wt) {
    __shared__ float lds[64][65];
    const int tid = threadIdx.x, tx = tid & 15, ty = tid >> 4;
    const int n0 = blockIdx.x * 64, k0 = blockIdx.y * 64;
    const size_t l = blockIdx.z;
    const float* src = W + (l * 2048 + (size_t)k0) * 4096 + n0;
#pragma unroll
    for (int rr = 0; rr < 4; ++rr) {
        int kr = rr * 16 + ty;
        f32x4 v = *(const f32x4*)(src + (size_t)kr * 4096 + tx * 4);
        lds[kr][tx*4+0] = v[0]; lds[kr][tx*4+1] = v[1];
        lds[kr][tx*4+2] = v[2]; lds[kr][tx*4+3] = v[3];
    }
    __syncthreads();
    __bf16* dhi = Wt + ((l * 2 + 0) * 4096 + (size_t)n0) * 2048 + k0;
    __bf16* dlo = Wt + ((l * 2 + 1) * 4096 + (size_t)n0) * 2048 + k0;
#pragma unroll
    for (int rr = 0; rr < 4; ++rr) {
        int nr = rr * 16 + ty;
        bf16x4 ohi, olo;
#pragma unroll
        for (int j = 0; j < 4; ++j) {
            float x = lds[tx*4+j][nr];
            __bf16 h = (__bf16)x;
            ohi[j] = h;
            olo[j] = (__bf16)(x - (float)h);
        }
        *(bf16x4*)(dhi + (size_t)nr * 2048 + tx * 4) = ohi;
        *(bf16x4*)(dlo + (size_t)nr * 2048 + tx * 4) = olo;
    }
}

// plain f32 -> bf16 (hi only), 8 elems/thread, exact grid
__global__ __launch_bounds__(256) void k_cvt(const float* __restrict__ in,
                                             __bf16* __restrict__ out) {
    size_t i = ((size_t)blockIdx.x * 256 + threadIdx.x) * 8;
    f32x4 v0 = *(const f32x4*)(in + i);
    f32x4 v1 = *(const f32x4*)(in + i + 4);
    bf16x8 o;
    o[0]=(__bf16)v0[0]; o[1]=(__bf16)v0[1]; o[2]=(__bf16)v0[2]; o[3]=(__bf16)v0[3];
    o[4]=(__bf16)v1[0]; o[5]=(__bf16)v1[1]; o[6]=(__bf16)v1[2]; o[7]=(__bf16)v1[3];
    *(bf16x8*)(out + i) = o;
}

// embedding gather -> time-major [t*32+b][1024] hi/lo bf16
__global__ __launch_bounds__(256) void k_embed(const int* __restrict__ idx,
                                               const float* __restrict__ emb,
                                               __bf16* __restrict__ xhi,
                                               __bf16* __restrict__ xlo) {
    const int row = blockIdx.x;            // t*32 + b
    const int t = row >> 5, b = row & 31;
    const int id = idx[b * SEQ + t];
    const int tid = threadIdx.x;
    f32x4 v = *(const f32x4*)(emb + (size_t)id * RNN + tid * 4);
    bf16x4 hi, lo;
#pragma unroll
    for (int j = 0; j < 4; ++j) {
        __bf16 h = (__bf16)v[j];
        hi[j] = h; lo[j] = (__bf16)(v[j] - (float)h);
    }
    *(bf16x4*)(xhi + (size_t)row * RNN + tid * 4) = hi;
    *(bf16x4*)(xlo + (size_t)row * RNN + tid * 4) = lo;
}

// ---------------------------------------------------------------------------
// Persistent 4-layer recurrence. 160 blocks x 256 threads, cooperative.
// Col-blocks (0..127): 32 z-cols each; W-hi slice in LDS (swizzled), W-lo
// from L2. Per step: [h-part + z write] sync [x-part(t+1) || gates] sync.
// Row-blocks (128..159): LN + gates + state for one batch row.
__global__ __launch_bounds__(256, 1) void k_rnn(
        const __bf16* __restrict__ Wt,    // [L][2][4096][2048]
        const float* __restrict__ bias,   // [L][4096]
        const float* __restrict__ ln_g,   // [L][5][1024]
        const float* __restrict__ ln_b,
        float* __restrict__ z,            // [32][4096]
        __bf16* __restrict__ hhi, __bf16* __restrict__ hlo,  // [32][1024]
        float* __restrict__ c,            // [32][1024]
        __bf16* __restrict__ xhi, __bf16* __restrict__ xlo)  // [SEQ*32][1024]
{
    cg::grid_group grid = cg::this_grid();
    __shared__ __bf16 wlds[32 * 2048];    // 128 KB W-hi slice, XOR-swizzled
    __shared__ float red[4][8];

    const int bk = blockIdx.x, tid = threadIdx.x;
    const int lane = tid & 63, w = tid >> 6;
    const int q = lane & 15, g = lane >> 4;
    const int ko = g * 8;
    const bool is_col = (bk < NCOLB);
    const bool is_row = (bk >= NCOLB);
    const int rb = bk - NCOLB;            // batch row for row-blocks

    // col-block geometry
    const int n_local = ((w >> 1) << 4) + q;   // 0..31
    const int ncol    = (bk << 5) + n_local;   // 0..4095
    const int mrow    = ((w & 1) << 4) + q;    // batch row of A-frag
    const int zr0     = ((w & 1) << 4) + (g << 2);
    const unsigned swz = (unsigned)(n_local & 7) << 4;
    const char* wrow = (const char*)wlds + (unsigned)n_local * 4096;

    const float inv = 1.f / (float)RNN;

    for (int l = 0; l < NLAY; ++l) {
        const __bf16* Wlo_l = Wt + ((size_t)(l * 2 + 1) * 4096) * 2048;
        const __bf16* wlo = Wlo_l + (size_t)ncol * 2048;  // this lane's col
        float bv = 0.f;
        f32x4 gi, bi, gj, bj, gf, bfv, go, bo, g4, b4;
        if (is_col) {
            bv = bias[l * 4096 + ncol];
            // stage W-hi slice (32 rows x 2048 k) into swizzled LDS
            const __bf16* src = Wt + ((size_t)(l * 2) * 4096 + ((size_t)bk << 5)) * 2048;
            for (int i = tid; i < 32 * 256; i += 256) {  // 16B chunks
                int r = i >> 8, cc = i & 255;
                bf16x8 v = *(const bf16x8*)(src + (size_t)r * 2048 + cc * 8);
                unsigned d = (unsigned)r * 4096 + (((unsigned)cc * 16) ^ ((unsigned)(r & 7) << 4));
                *(bf16x8*)((char*)wlds + d) = v;
            }
        } else {
            const float* g5 = ln_g + (size_t)l * 5 * RNN;
            const float* b5 = ln_b + (size_t)l * 5 * RNN;
            gi = *(const f32x4*)(g5 + 0*RNN + tid*4); bi = *(const f32x4*)(b5 + 0*RNN + tid*4);
            gj = *(const f32x4*)(g5 + 1*RNN + tid*4); bj = *(const f32x4*)(b5 + 1*RNN + tid*4);
            gf = *(const f32x4*)(g5 + 2*RNN + tid*4); bfv= *(const f32x4*)(b5 + 2*RNN + tid*4);
            go = *(const f32x4*)(g5 + 3*RNN + tid*4); bo = *(const f32x4*)(b5 + 3*RNN + tid*4);
            g4 = *(const f32x4*)(g5 + 4*RNN + tid*4); b4 = *(const f32x4*)(b5 + 4*RNN + tid*4);
        }
        __syncthreads();

        // split-bf16 partial matmul: this lane's (m-tile, n-col) over K=1024
        // starting at kbase (0 = x-part, RNN = h-part).
        auto mm_part = [&](const __bf16* ah_, const __bf16* al_, int kbase) {
            f32x4 a = {0.f, 0.f, 0.f, 0.f};
#pragma unroll 4
            for (int k0 = 0; k0 < RNN; k0 += 32) {
                unsigned koff = ((unsigned)((kbase + k0 + ko) * 2)) ^ swz;
                bf16x8 bhf = *(const bf16x8*)(wrow + koff);
                bf16x8 blf = *(const bf16x8*)(wlo + kbase + k0 + ko);
                bf16x8 ahf = *(const bf16x8*)(ah_ + k0 + ko);
                bf16x8 alf = *(const bf16x8*)(al_ + k0 + ko);
                a = __builtin_amdgcn_mfma_f32_16x16x32_bf16(ahf, bhf, a, 0, 0, 0);
                a = __builtin_amdgcn_mfma_f32_16x16x32_bf16(alf, bhf, a, 0, 0, 0);
                a = __builtin_amdgcn_mfma_f32_16x16x32_bf16(ahf, blf, a, 0, 0, 0);
            }
            return a;
        };

        // prologue: x-part for t=0 (x rows valid: embed or previous layer)
        f32x4 accx = {0.f, 0.f, 0.f, 0.f};
        if (is_col)
            accx = mm_part(xhi + (size_t)mrow * RNN, xlo + (size_t)mrow * RNN, 0);

        for (int t = 0; t < SEQ; ++t) {
            // ---- phase A: finish z_t = accx + h-part + bias ----
            if (is_col) {
                f32x4 acc = accx;
                if (t > 0) {
                    f32x4 ah = mm_part(hhi + (size_t)mrow * RNN,
                                       hlo + (size_t)mrow * RNN, RNN);
                    acc[0] += ah[0]; acc[1] += ah[1]; acc[2] += ah[2]; acc[3] += ah[3];
                }
#pragma unroll
                for (int r = 0; r < 4; ++r)
                    z[(size_t)(zr0 + r) * 4096 + ncol] = acc[r] + bv;
            }
            __threadfence();
            grid.sync();   // z complete

            // ---- overlap: col-blocks prefetch x-part(t+1); row-blocks gates ----
            if (is_col) {
                if (t + 1 < SEQ)
                    accx = mm_part(xhi + ((size_t)(t + 1) * BATCH + mrow) * RNN,
                                   xlo + ((size_t)(t + 1) * BATCH + mrow) * RNN, 0);
            } else {
                const int b = rb;
                const f32x4* zr = (const f32x4*)(z + (size_t)b * 4096);
                f32x4 zi = zr[tid], zjv = zr[256 + tid], zfv = zr[512 + tid], zov = zr[768 + tid];
                float s[8];
                s[0] = zi[0]+zi[1]+zi[2]+zi[3];
                s[1] = zi[0]*zi[0]+zi[1]*zi[1]+zi[2]*zi[2]+zi[3]*zi[3];
                s[2] = zjv[0]+zjv[1]+zjv[2]+zjv[3];
                s[3] = zjv[0]*zjv[0]+zjv[1]*zjv[1]+zjv[2]*zjv[2]+zjv[3]*zjv[3];
                s[4] = zfv[0]+zfv[1]+zfv[2]+zfv[3];
                s[5] = zfv[0]*zfv[0]+zfv[1]*zfv[1]+zfv[2]*zfv[2]+zfv[3]*zfv[3];
                s[6] = zov[0]+zov[1]+zov[2]+zov[3];
                s[7] = zov[0]*zov[0]+zov[1]*zov[1]+zov[2]*zov[2]+zov[3]*zov[3];
#pragma unroll
                for (int o = 32; o; o >>= 1)
#pragma unroll
                    for (int i = 0; i < 8; ++i) s[i] += __shfl_xor(s[i], o);
                if (lane == 0) {
#pragma unroll
                    for (int i = 0; i < 8; ++i) red[w][i] = s[i];
                }
                __syncthreads();
                float tot[8];
#pragma unroll
                for (int i = 0; i < 8; ++i) tot[i] = red[0][i]+red[1][i]+red[2][i]+red[3][i];

                float mi = tot[0]*inv, ri = rsqrtf(tot[1]*inv - mi*mi + 1e-5f);
                float mj = tot[2]*inv, rj = rsqrtf(tot[3]*inv - mj*mj + 1e-5f);
                float mf = tot[4]*inv, rf = rsqrtf(tot[5]*inv - mf*mf + 1e-5f);
                float mo = tot[6]*inv, ro = rsqrtf(tot[7]*inv - mo*mo + 1e-5f);

                f32x4 cold = {0.f, 0.f, 0.f, 0.f};
                if (t > 0) cold = *(const f32x4*)(c + (size_t)b * RNN + tid * 4);

                f32x4 cnew, onrm;
                float cs = 0.f, cq = 0.f;
#pragma unroll
                for (int j = 0; j < 4; ++j) {
                    float iv = (zi[j]-mi)*ri*gi[j] + bi[j];
                    float jv = (zjv[j]-mj)*rj*gj[j] + bj[j];
                    float fv = (zfv[j]-mf)*rf*gf[j] + bfv[j];
                    float ov = (zov[j]-mo)*ro*go[j] + bo[j];
                    float cc = cold[j] * sigm(fv + 1.0f) + sigm(iv) * tanhf(jv);
                    cnew[j] = cc; onrm[j] = ov;
                    cs += cc; cq += cc*cc;
                }
                *(f32x4*)(c + (size_t)b * RNN + tid * 4) = cnew;

                __syncthreads();   // protect red[] reuse
                float s2a = cs, s2b = cq;
#pragma unroll
                for (int o = 32; o; o >>= 1) { s2a += __shfl_xor(s2a, o); s2b += __shfl_xor(s2b, o); }
                if (lane == 0) { red[w][0] = s2a; red[w][1] = s2b; }
                __syncthreads();
                float mc = (red[0][0]+red[1][0]+red[2][0]+red[3][0]) * inv;
                float vc = (red[0][1]+red[1][1]+red[2][1]+red[3][1]) * inv - mc*mc;
                float rc = rsqrtf(vc + 1e-5f);

                bf16x4 hh, hl;
#pragma unroll
                for (int j = 0; j < 4; ++j) {
                    float cn = (cnew[j]-mc)*rc*g4[j] + b4[j];
                    float h = tanhf(cn) * sigm(onrm[j]);
                    __bf16 a = (__bf16)h;
                    hh[j] = a; hl[j] = (__bf16)(h - (float)a);
                }
                *(bf16x4*)(hhi + (size_t)b * RNN + tid * 4) = hh;
                *(bf16x4*)(hlo + (size_t)b * RNN + tid * 4) = hl;
                *(bf16x4*)(xhi + ((size_t)t * BATCH + b) * RNN + tid * 4) = hh;
                *(bf16x4*)(xlo + ((size_t)t * BATCH + b) * RNN + tid * 4) = hl;
            }
            __threadfence();
            grid.sync();   // h_t + x_t complete
        }
    }
}

// ---------------------------------------------------------------------------
// logits[m][v] = sum_k h[m][k]*smw[v][k] + smb[v], m = b*128+t; plain bf16.
// Source row in time-major buffer = (m&127)*32 + (m>>7).
__global__ __launch_bounds__(256) void k_proj(const __bf16* __restrict__ xs,
                                              const __bf16* __restrict__ wv,
                                              const float* __restrict__ sb,
                                              float* __restrict__ out) {
    const int tid = threadIdx.x;
    const int lane = tid & 63, w = tid >> 6;
    const int g = lane >> 4, q = lane & 15;
    const int n = blockIdx.x * 64 + w * 16 + q;
    const int m0 = blockIdx.y * 64;
    const int ko = g * 8;
    f32x4 acc[4] = {{0,0,0,0},{0,0,0,0},{0,0,0,0},{0,0,0,0}};
    const __bf16* arow[4];
#pragma unroll
    for (int mt = 0; mt < 4; ++mt) {
        int m = m0 + mt * 16 + q;
        arow[mt] = xs + (size_t)((m & 127) * 32 + (m >> 7)) * RNN;
    }
    const __bf16* brow = wv + (size_t)n * RNN;
#pragma unroll 2
    for (int k0 = 0; k0 < RNN; k0 += 32) {
        bf16x8 bfr = *(const bf16x8*)(brow + k0 + ko);
#pragma unroll
        for (int mt = 0; mt < 4; ++mt) {
            bf16x8 afr = *(const bf16x8*)(arow[mt] + k0 + ko);
            acc[mt] = __builtin_amdgcn_mfma_f32_16x16x32_bf16(afr, bfr, acc[mt], 0, 0, 0);
        }
    }
    const float bv = sb[n];
#pragma unroll
    for (int mt = 0; mt < 4; ++mt)
#pragma unroll
        for (int r = 0; r < 4; ++r) {
            int m = m0 + mt * 16 + g * 4 + r;
            out[(size_t)m * VOCAB + n] = acc[mt][r] + bv;
        }
}

// ---------------------------------------------------------------------------
extern "C" void kernel_launch(void* const* d_in, const int* in_sizes, int n_in,
                              void* d_out, int out_size, void* d_ws, size_t ws_size,
                              hipStream_t stream) {
    const int*   input = (const int*)  d_in[0];
    const float* emb   = (const float*)d_in[1];
    const float* W     = (const float*)d_in[2];
    const float* bias  = (const float*)d_in[3];
    const float* ln_g  = (const float*)d_in[4];
    const float* ln_b  = (const float*)d_in[5];
    const float* smw   = (const float*)d_in[6];
    const float* smb   = (const float*)d_in[7];
    float* out = (float*)d_out;

    char* p = (char*)d_ws;
    auto alloc = [&](size_t bytes) { char* r = p; p += (bytes + 255) & ~(size_t)255; return r; };
    __bf16* Wt   = (__bf16*)alloc((size_t)NLAY * 2 * 4096 * 2048 * 2); // 134.2 MB
    __bf16* smwb = (__bf16*)alloc((size_t)VOCAB * RNN * 2);            // 65.5 MB
    __bf16* xhi  = (__bf16*)alloc((size_t)SEQ * BATCH * RNN * 2);      // 8.4 MB
    __bf16* xlo  = (__bf16*)alloc((size_t)SEQ * BATCH * RNN * 2);      // 8.4 MB
    float*  z    = (float*) alloc((size_t)BATCH * 4096 * 4);           // 512 KB
    __bf16* hhi  = (__bf16*)alloc((size_t)BATCH * RNN * 2);            // 64 KB
    __bf16* hlo  = (__bf16*)alloc((size_t)BATCH * RNN * 2);            // 64 KB
    float*  c    = (float*) alloc((size_t)BATCH * RNN * 4);            // 128 KB

    k_cvt_w<<<dim3(64, 32, NLAY), 256, 0, stream>>>(W, Wt);
    k_cvt<<<(VOCAB * RNN) / (8 * 256), 256, 0, stream>>>(smw, smwb);
    k_embed<<<SEQ * BATCH, 256, 0, stream>>>(input, emb, xhi, xlo);

    {
        const __bf16* Wt_ = Wt;
        const float *bias_ = bias, *lng_ = ln_g, *lnb_ = ln_b;
        float* z_ = z;
        __bf16 *hhi_ = hhi, *hlo_ = hlo;
        float* c_ = c;
        __bf16 *xhi_ = xhi, *xlo_ = xlo;
        void* args[] = {(void*)&Wt_, (void*)&bias_, (void*)&lng_, (void*)&lnb_,
                        (void*)&z_, (void*)&hhi_, (void*)&hlo_, (void*)&c_,
                        (void*)&xhi_, (void*)&xlo_};
        hipLaunchCooperativeKernel((const void*)k_rnn,
                                   dim3(GBLK), dim3(256), args, 0, stream);
    }

    // final layer output (bf16 hi) lives in xhi (time-major)
    k_proj<<<dim3(VOCAB / 64, 4096 / 64), 256, 0, stream>>>(xhi, smwb, smb, out);
}

// Round 5
// 38189.868 us; speedup vs baseline: 1.2373x; 1.2373x over previous
//
#include <hip/hip_runtime.h>
#include <hip/hip_bf16.h>
#include <hip/hip_cooperative_groups.h>

namespace cg = cooperative_groups;

// CharRNN: embed -> 4x (LayerNorm-LSTM over T=128) -> projection to vocab.
// Round 4: per layer = parallel x-GEMM (zx) + cooperative recurrence kernel
// with BOTH Wh planes (hi+lo) pinned in LDS (128 KB/block, stored in exact
// lane-read order -> conflict-free linear ds_read_b128). Zero W global
// traffic inside the 512-step loop. Grid 128 blocks; gates in blocks 0..31.

typedef __bf16 bf16x8 __attribute__((ext_vector_type(8)));
typedef __bf16 bf16x4 __attribute__((ext_vector_type(4)));
typedef float  f32x4  __attribute__((ext_vector_type(4)));

#define VOCAB 32000
#define BATCH 32
#define SEQ   128
#define RNN   1024
#define NLAY  4
#define GBLK  128

__device__ __forceinline__ float sigm(float x) { return 1.f / (1.f + __expf(-x)); }

// ---------------------------------------------------------------------------
// W [L][2048][4096] f32 -> Wt [L][2 planes (hi,lo)][4096][2048] bf16,
// transposed to [n][k]. k 0..1023 = x-part (Wx), k 1024..2047 = h-part (Wh).
__global__ __launch_bounds__(256) void k_cvt_w(const float* __restrict__ W,
                                               __bf16* __restrict__ Wt) {
    __shared__ float lds[64][65];
    const int tid = threadIdx.x, tx = tid & 15, ty = tid >> 4;
    const int n0 = blockIdx.x * 64, k0 = blockIdx.y * 64;
    const size_t l = blockIdx.z;
    const float* src = W + (l * 2048 + (size_t)k0) * 4096 + n0;
#pragma unroll
    for (int rr = 0; rr < 4; ++rr) {
        int kr = rr * 16 + ty;
        f32x4 v = *(const f32x4*)(src + (size_t)kr * 4096 + tx * 4);
        lds[kr][tx*4+0] = v[0]; lds[kr][tx*4+1] = v[1];
        lds[kr][tx*4+2] = v[2]; lds[kr][tx*4+3] = v[3];
    }
    __syncthreads();
    __bf16* dhi = Wt + ((l * 2 + 0) * 4096 + (size_t)n0) * 2048 + k0;
    __bf16* dlo = Wt + ((l * 2 + 1) * 4096 + (size_t)n0) * 2048 + k0;
#pragma unroll
    for (int rr = 0; rr < 4; ++rr) {
        int nr = rr * 16 + ty;
        bf16x4 ohi, olo;
#pragma unroll
        for (int j = 0; j < 4; ++j) {
            float x = lds[tx*4+j][nr];
            __bf16 h = (__bf16)x;
            ohi[j] = h;
            olo[j] = (__bf16)(x - (float)h);
        }
        *(bf16x4*)(dhi + (size_t)nr * 2048 + tx * 4) = ohi;
        *(bf16x4*)(dlo + (size_t)nr * 2048 + tx * 4) = olo;
    }
}

// plain f32 -> bf16 (hi only), 8 elems/thread, exact grid
__global__ __launch_bounds__(256) void k_cvt(const float* __restrict__ in,
                                             __bf16* __restrict__ out) {
    size_t i = ((size_t)blockIdx.x * 256 + threadIdx.x) * 8;
    f32x4 v0 = *(const f32x4*)(in + i);
    f32x4 v1 = *(const f32x4*)(in + i + 4);
    bf16x8 o;
    o[0]=(__bf16)v0[0]; o[1]=(__bf16)v0[1]; o[2]=(__bf16)v0[2]; o[3]=(__bf16)v0[3];
    o[4]=(__bf16)v1[0]; o[5]=(__bf16)v1[1]; o[6]=(__bf16)v1[2]; o[7]=(__bf16)v1[3];
    *(bf16x8*)(out + i) = o;
}

// embedding gather -> time-major [t*32+b][1024] hi/lo bf16
__global__ __launch_bounds__(256) void k_embed(const int* __restrict__ idx,
                                               const float* __restrict__ emb,
                                               __bf16* __restrict__ xhi,
                                               __bf16* __restrict__ xlo) {
    const int row = blockIdx.x;            // t*32 + b
    const int t = row >> 5, b = row & 31;
    const int id = idx[b * SEQ + t];
    const int tid = threadIdx.x;
    f32x4 v = *(const f32x4*)(emb + (size_t)id * RNN + tid * 4);
    bf16x4 hi, lo;
#pragma unroll
    for (int j = 0; j < 4; ++j) {
        __bf16 h = (__bf16)v[j];
        hi[j] = h; lo[j] = (__bf16)(v[j] - (float)h);
    }
    *(bf16x4*)(xhi + (size_t)row * RNN + tid * 4) = hi;
    *(bf16x4*)(xlo + (size_t)row * RNN + tid * 4) = lo;
}

// ---------------------------------------------------------------------------
// zx[4096][4096] = X @ Wx + bias, 3-term split bf16 MFMA (fp32-grade).
// Block = 64(M) x 64(N); wave = 4 m-tiles x 16 n.
__global__ __launch_bounds__(256) void k_xgemm(const __bf16* __restrict__ xhi,
                                               const __bf16* __restrict__ xlo,
                                               const __bf16* __restrict__ Wt, // layer base
                                               const float* __restrict__ bias,
                                               float* __restrict__ zx) {
    const int tid = threadIdx.x;
    const int lane = tid & 63, w = tid >> 6;
    const int g = lane >> 4, q = lane & 15;
    const int n = blockIdx.x * 64 + w * 16 + q;
    const int m0 = blockIdx.y * 64;
    const int ko = g * 8;
    const __bf16* bh = Wt + (size_t)n * 2048;              // hi plane, k in [0,1024)
    const __bf16* bl = Wt + ((size_t)4096 + n) * 2048;     // lo plane
    f32x4 acc[4] = {{0,0,0,0},{0,0,0,0},{0,0,0,0},{0,0,0,0}};
    const __bf16 *ah[4], *al[4];
#pragma unroll
    for (int mt = 0; mt < 4; ++mt) {
        int m = m0 + mt * 16 + q;
        ah[mt] = xhi + (size_t)m * RNN;
        al[mt] = xlo + (size_t)m * RNN;
    }
#pragma unroll 2
    for (int k0 = 0; k0 < RNN; k0 += 32) {
        bf16x8 bhf = *(const bf16x8*)(bh + k0 + ko);
        bf16x8 blf = *(const bf16x8*)(bl + k0 + ko);
#pragma unroll
        for (int mt = 0; mt < 4; ++mt) {
            bf16x8 ahf = *(const bf16x8*)(ah[mt] + k0 + ko);
            bf16x8 alf = *(const bf16x8*)(al[mt] + k0 + ko);
            acc[mt] = __builtin_amdgcn_mfma_f32_16x16x32_bf16(ahf, bhf, acc[mt], 0, 0, 0);
            acc[mt] = __builtin_amdgcn_mfma_f32_16x16x32_bf16(alf, bhf, acc[mt], 0, 0, 0);
            acc[mt] = __builtin_amdgcn_mfma_f32_16x16x32_bf16(ahf, blf, acc[mt], 0, 0, 0);
        }
    }
    const float bv = bias[n];
#pragma unroll
    for (int mt = 0; mt < 4; ++mt)
#pragma unroll
        for (int r = 0; r < 4; ++r) {
            int m = m0 + mt * 16 + g * 4 + r;
            zx[(size_t)m * 4096 + n] = acc[mt][r] + bv;
        }
}

// ---------------------------------------------------------------------------
// Persistent per-layer recurrence. 128 blocks x 256 threads, cooperative.
// Each block owns 32 z-cols; Wh hi+lo pinned in LDS in lane-read order:
// plane[(nt*32+kc)*512 + lane*8 + j] = Wh[bk*32+nt*16+(lane&15)][kc*32+(lane>>4)*8+j]
// -> every ds_read_b128 is 64 lanes x contiguous 16B (conflict-free).
// Per step: phase A z = zx[t] + h@Wh; sync; phase B gates (blocks 0..31); sync.
__global__ __launch_bounds__(256, 1) void k_rnn(
        const __bf16* __restrict__ Wl,    // layer base [2][4096][2048]
        const float* __restrict__ zx,     // [SEQ*32][4096] (bias folded)
        float* __restrict__ z,            // [32][4096] scratch
        __bf16* __restrict__ hhi, __bf16* __restrict__ hlo,  // [32][1024]
        float* __restrict__ c,            // [32][1024]
        __bf16* __restrict__ xhi, __bf16* __restrict__ xlo,  // [SEQ*32][1024]
        const float* __restrict__ g5, const float* __restrict__ b5)
{
    cg::grid_group grid = cg::this_grid();
    __shared__ __bf16 wl[2][32768];       // 128 KB: Wh hi, lo
    __shared__ float red[4][8];

    const int bk = blockIdx.x, tid = threadIdx.x;
    const int lane = tid & 63, w = tid >> 6;
    const int q = lane & 15, g = lane >> 4;
    const int mt = w & 1, nt = w >> 1;
    const int ncol = (bk << 5) + (nt << 4) + q;
    const int zr0  = (mt << 4) + (g << 2);

    // ---- stage Wh hi+lo into LDS (lane-read order) ----
    {
        const __bf16* hi_src = Wl + ((size_t)(bk << 5)) * 2048 + RNN;
        const __bf16* lo_src = Wl + ((size_t)(4096 + (bk << 5))) * 2048 + RNN;
        for (int i = tid; i < 8192; i += 256) {
            int pl = i >> 12, rem = i & 4095;
            int r = rem >> 7, cc = rem & 127;
            const __bf16* s = (pl ? lo_src : hi_src) + (size_t)r * 2048 + cc * 8;
            bf16x8 v = *(const bf16x8*)s;
            int rnt = r >> 4, rq = r & 15, kc = cc >> 2, rg = cc & 3;
            *(bf16x8*)&wl[pl][((rnt * 32 + kc) << 9) + ((rg * 16 + rq) << 3)] = v;
        }
    }

    // ---- gate-block constants (blocks 0..31) ----
    const bool is_gate = (bk < BATCH);
    f32x4 gi, bi, gj, bj, gf, bfv, go, bo, g4, b4;
    if (is_gate) {
        gi = *(const f32x4*)(g5 + 0*RNN + tid*4); bi = *(const f32x4*)(b5 + 0*RNN + tid*4);
        gj = *(const f32x4*)(g5 + 1*RNN + tid*4); bj = *(const f32x4*)(b5 + 1*RNN + tid*4);
        gf = *(const f32x4*)(g5 + 2*RNN + tid*4); bfv= *(const f32x4*)(b5 + 2*RNN + tid*4);
        go = *(const f32x4*)(g5 + 3*RNN + tid*4); bo = *(const f32x4*)(b5 + 3*RNN + tid*4);
        g4 = *(const f32x4*)(g5 + 4*RNN + tid*4); b4 = *(const f32x4*)(b5 + 4*RNN + tid*4);
    }
    const float inv = 1.f / (float)RNN;
    __syncthreads();   // LDS staged

    const __bf16* bh_base = &wl[0][(nt * 32) << 9] + (lane << 3);
    const __bf16* bl_base = &wl[1][(nt * 32) << 9] + (lane << 3);

    for (int t = 0; t < SEQ; ++t) {
        // ---- phase A: z_t = zx[t] + h_{t-1} @ Wh ----
        {
            f32x4 acc = {0.f, 0.f, 0.f, 0.f};
            if (t > 0) {
                const __bf16* ah = hhi + (size_t)((mt << 4) + q) * RNN;
                const __bf16* al = hlo + (size_t)((mt << 4) + q) * RNN;
#pragma unroll 4
                for (int kc = 0; kc < 32; ++kc) {
                    bf16x8 bhf = *(const bf16x8*)(bh_base + (kc << 9));
                    bf16x8 blf = *(const bf16x8*)(bl_base + (kc << 9));
                    bf16x8 ahf = *(const bf16x8*)(ah + (kc << 5) + (g << 3));
                    bf16x8 alf = *(const bf16x8*)(al + (kc << 5) + (g << 3));
                    acc = __builtin_amdgcn_mfma_f32_16x16x32_bf16(ahf, bhf, acc, 0, 0, 0);
                    acc = __builtin_amdgcn_mfma_f32_16x16x32_bf16(alf, bhf, acc, 0, 0, 0);
                    acc = __builtin_amdgcn_mfma_f32_16x16x32_bf16(ahf, blf, acc, 0, 0, 0);
                }
            }
            const float* zxp = zx + ((size_t)t * BATCH + zr0) * 4096 + ncol;
#pragma unroll
            for (int r = 0; r < 4; ++r)
                z[(size_t)(zr0 + r) * 4096 + ncol] = acc[r] + zxp[(size_t)r * 4096];
        }
        __threadfence();
        grid.sync();   // z complete

        // ---- phase B: gates (blocks 0..31) ----
        if (is_gate) {
            const int b = bk;
            const f32x4* zr = (const f32x4*)(z + (size_t)b * 4096);
            f32x4 zi = zr[tid], zjv = zr[256 + tid], zfv = zr[512 + tid], zov = zr[768 + tid];
            float s[8];
            s[0] = zi[0]+zi[1]+zi[2]+zi[3];
            s[1] = zi[0]*zi[0]+zi[1]*zi[1]+zi[2]*zi[2]+zi[3]*zi[3];
            s[2] = zjv[0]+zjv[1]+zjv[2]+zjv[3];
            s[3] = zjv[0]*zjv[0]+zjv[1]*zjv[1]+zjv[2]*zjv[2]+zjv[3]*zjv[3];
            s[4] = zfv[0]+zfv[1]+zfv[2]+zfv[3];
            s[5] = zfv[0]*zfv[0]+zfv[1]*zfv[1]+zfv[2]*zfv[2]+zfv[3]*zfv[3];
            s[6] = zov[0]+zov[1]+zov[2]+zov[3];
            s[7] = zov[0]*zov[0]+zov[1]*zov[1]+zov[2]*zov[2]+zov[3]*zov[3];
#pragma unroll
            for (int o = 32; o; o >>= 1)
#pragma unroll
                for (int i = 0; i < 8; ++i) s[i] += __shfl_xor(s[i], o);
            if (lane == 0) {
#pragma unroll
                for (int i = 0; i < 8; ++i) red[w][i] = s[i];
            }
            __syncthreads();
            float tot[8];
#pragma unroll
            for (int i = 0; i < 8; ++i) tot[i] = red[0][i]+red[1][i]+red[2][i]+red[3][i];

            float mi = tot[0]*inv, ri = rsqrtf(tot[1]*inv - mi*mi + 1e-5f);
            float mj = tot[2]*inv, rj = rsqrtf(tot[3]*inv - mj*mj + 1e-5f);
            float mf = tot[4]*inv, rf = rsqrtf(tot[5]*inv - mf*mf + 1e-5f);
            float mo = tot[6]*inv, ro = rsqrtf(tot[7]*inv - mo*mo + 1e-5f);

            f32x4 cold = {0.f, 0.f, 0.f, 0.f};
            if (t > 0) cold = *(const f32x4*)(c + (size_t)b * RNN + tid * 4);

            f32x4 cnew, onrm;
            float cs = 0.f, cq = 0.f;
#pragma unroll
            for (int j = 0; j < 4; ++j) {
                float iv = (zi[j]-mi)*ri*gi[j] + bi[j];
                float jv = (zjv[j]-mj)*rj*gj[j] + bj[j];
                float fv = (zfv[j]-mf)*rf*gf[j] + bfv[j];
                float ov = (zov[j]-mo)*ro*go[j] + bo[j];
                float cc = cold[j] * sigm(fv + 1.0f) + sigm(iv) * tanhf(jv);
                cnew[j] = cc; onrm[j] = ov;
                cs += cc; cq += cc*cc;
            }
            *(f32x4*)(c + (size_t)b * RNN + tid * 4) = cnew;

            __syncthreads();   // protect red[] reuse
            float s2a = cs, s2b = cq;
#pragma unroll
            for (int o = 32; o; o >>= 1) { s2a += __shfl_xor(s2a, o); s2b += __shfl_xor(s2b, o); }
            if (lane == 0) { red[w][0] = s2a; red[w][1] = s2b; }
            __syncthreads();
            float mc = (red[0][0]+red[1][0]+red[2][0]+red[3][0]) * inv;
            float vc = (red[0][1]+red[1][1]+red[2][1]+red[3][1]) * inv - mc*mc;
            float rc = rsqrtf(vc + 1e-5f);

            bf16x4 hh, hl;
#pragma unroll
            for (int j = 0; j < 4; ++j) {
                float cn = (cnew[j]-mc)*rc*g4[j] + b4[j];
                float h = tanhf(cn) * sigm(onrm[j]);
                __bf16 a = (__bf16)h;
                hh[j] = a; hl[j] = (__bf16)(h - (float)a);
            }
            *(bf16x4*)(hhi + (size_t)b * RNN + tid * 4) = hh;
            *(bf16x4*)(hlo + (size_t)b * RNN + tid * 4) = hl;
            *(bf16x4*)(xhi + ((size_t)t * BATCH + b) * RNN + tid * 4) = hh;
            *(bf16x4*)(xlo + ((size_t)t * BATCH + b) * RNN + tid * 4) = hl;
        }
        __threadfence();
        grid.sync();   // h_t complete
    }
}

// ---------------------------------------------------------------------------
// logits[m][v] = sum_k h[m][k]*smw[v][k] + smb[v], m = b*128+t; plain bf16.
// Source row in time-major buffer = (m&127)*32 + (m>>7).
__global__ __launch_bounds__(256) void k_proj(const __bf16* __restrict__ xs,
                                              const __bf16* __restrict__ wv,
                                              const float* __restrict__ sb,
                                              float* __restrict__ out) {
    const int tid = threadIdx.x;
    const int lane = tid & 63, w = tid >> 6;
    const int g = lane >> 4, q = lane & 15;
    const int n = blockIdx.x * 64 + w * 16 + q;
    const int m0 = blockIdx.y * 64;
    const int ko = g * 8;
    f32x4 acc[4] = {{0,0,0,0},{0,0,0,0},{0,0,0,0},{0,0,0,0}};
    const __bf16* arow[4];
#pragma unroll
    for (int mt = 0; mt < 4; ++mt) {
        int m = m0 + mt * 16 + q;
        arow[mt] = xs + (size_t)((m & 127) * 32 + (m >> 7)) * RNN;
    }
    const __bf16* brow = wv + (size_t)n * RNN;
#pragma unroll 2
    for (int k0 = 0; k0 < RNN; k0 += 32) {
        bf16x8 bfr = *(const bf16x8*)(brow + k0 + ko);
#pragma unroll
        for (int mt = 0; mt < 4; ++mt) {
            bf16x8 afr = *(const bf16x8*)(arow[mt] + k0 + ko);
            acc[mt] = __builtin_amdgcn_mfma_f32_16x16x32_bf16(afr, bfr, acc[mt], 0, 0, 0);
        }
    }
    const float bv = sb[n];
#pragma unroll
    for (int mt = 0; mt < 4; ++mt)
#pragma unroll
        for (int r = 0; r < 4; ++r) {
            int m = m0 + mt * 16 + g * 4 + r;
            out[(size_t)m * VOCAB + n] = acc[mt][r] + bv;
        }
}

// ---------------------------------------------------------------------------
extern "C" void kernel_launch(void* const* d_in, const int* in_sizes, int n_in,
                              void* d_out, int out_size, void* d_ws, size_t ws_size,
                              hipStream_t stream) {
    const int*   input = (const int*)  d_in[0];
    const float* emb   = (const float*)d_in[1];
    const float* W     = (const float*)d_in[2];
    const float* bias  = (const float*)d_in[3];
    const float* ln_g  = (const float*)d_in[4];
    const float* ln_b  = (const float*)d_in[5];
    const float* smw   = (const float*)d_in[6];
    const float* smb   = (const float*)d_in[7];
    float* out = (float*)d_out;

    char* p = (char*)d_ws;
    auto alloc = [&](size_t bytes) { char* r = p; p += (bytes + 255) & ~(size_t)255; return r; };
    __bf16* Wt   = (__bf16*)alloc((size_t)NLAY * 2 * 4096 * 2048 * 2); // 134.2 MB
    __bf16* smwb = (__bf16*)alloc((size_t)VOCAB * RNN * 2);            // 65.5 MB
    __bf16* xhi  = (__bf16*)alloc((size_t)SEQ * BATCH * RNN * 2);      // 8.4 MB
    __bf16* xlo  = (__bf16*)alloc((size_t)SEQ * BATCH * RNN * 2);      // 8.4 MB
    float*  zx   = (float*) alloc((size_t)SEQ * BATCH * 4096 * 4);     // 67.1 MB
    float*  z    = (float*) alloc((size_t)BATCH * 4096 * 4);           // 512 KB
    __bf16* hhi  = (__bf16*)alloc((size_t)BATCH * RNN * 2);            // 64 KB
    __bf16* hlo  = (__bf16*)alloc((size_t)BATCH * RNN * 2);            // 64 KB
    float*  c    = (float*) alloc((size_t)BATCH * RNN * 4);            // 128 KB

    k_cvt_w<<<dim3(64, 32, NLAY), 256, 0, stream>>>(W, Wt);
    k_cvt<<<(VOCAB * RNN) / (8 * 256), 256, 0, stream>>>(smw, smwb);
    k_embed<<<SEQ * BATCH, 256, 0, stream>>>(input, emb, xhi, xlo);

    for (int l = 0; l < NLAY; ++l) {
        const __bf16* Wl  = Wt + (size_t)l * 2 * 4096 * 2048;
        const float*  bl  = bias + (size_t)l * 4096;
        const float*  gl  = ln_g + (size_t)l * 5 * RNN;
        const float*  bbl = ln_b + (size_t)l * 5 * RNN;
        // x-part for all timesteps (parallel GEMM, bias folded)
        k_xgemm<<<dim3(64, 64), 256, 0, stream>>>(xhi, xlo, Wl, bl, zx);
        // recurrence: cooperative, Wh fully in LDS
        {
            const __bf16* Wl_ = Wl;
            const float*  zx_ = zx;
            float* z_ = z;
            __bf16 *hhi_ = hhi, *hlo_ = hlo;
            float* c_ = c;
            __bf16 *xhi_ = xhi, *xlo_ = xlo;
            const float *gl_ = gl, *bbl_ = bbl;
            void* args[] = {(void*)&Wl_, (void*)&zx_, (void*)&z_,
                            (void*)&hhi_, (void*)&hlo_, (void*)&c_,
                            (void*)&xhi_, (void*)&xlo_, (void*)&gl_, (void*)&bbl_};
            hipLaunchCooperativeKernel((const void*)k_rnn,
                                       dim3(GBLK), dim3(256), args, 0, stream);
        }
    }
    // final layer output (bf16 hi) lives in xhi (time-major)
    k_proj<<<dim3(VOCAB / 64, 4096 / 64), 256, 0, stream>>>(xhi, smwb, smb, out);
}

// Round 6
// 37527.850 us; speedup vs baseline: 1.2591x; 1.0176x over previous
//
#include <hip/hip_runtime.h>
#include <hip/hip_bf16.h>
#include <hip/hip_cooperative_groups.h>

namespace cg = cooperative_groups;

// CharRNN: embed -> 4x (LayerNorm-LSTM over T=128) -> projection to vocab.
// Round 5: round-4 dataflow (Wh hi+lo pinned in LDS, zx precomputed per
// layer) with cg::grid.sync() replaced by a hand-rolled two-level barrier
// (group counters -> root -> monotonic generation flag, leader-only spin).
// Cooperative launch kept only for the co-residency guarantee. Phase-A MFMA
// chain split into 3 independent accumulators; zx loads hoisted.

typedef __bf16 bf16x8 __attribute__((ext_vector_type(8)));
typedef __bf16 bf16x4 __attribute__((ext_vector_type(4)));
typedef float  f32x4  __attribute__((ext_vector_type(4)));

#define VOCAB 32000
#define BATCH 32
#define SEQ   128
#define RNN   1024
#define NLAY  4
#define GBLK  128

__device__ __forceinline__ float sigm(float x) { return 1.f / (1.f + __expf(-x)); }

// ---------------------------------------------------------------------------
// W [L][2048][4096] f32 -> Wt [L][2 planes (hi,lo)][4096][2048] bf16,
// transposed to [n][k]. k 0..1023 = x-part (Wx), k 1024..2047 = h-part (Wh).
__global__ __launch_bounds__(256) void k_cvt_w(const float* __restrict__ W,
                                               __bf16* __restrict__ Wt) {
    __shared__ float lds[64][65];
    const int tid = threadIdx.x, tx = tid & 15, ty = tid >> 4;
    const int n0 = blockIdx.x * 64, k0 = blockIdx.y * 64;
    const size_t l = blockIdx.z;
    const float* src = W + (l * 2048 + (size_t)k0) * 4096 + n0;
#pragma unroll
    for (int rr = 0; rr < 4; ++rr) {
        int kr = rr * 16 + ty;
        f32x4 v = *(const f32x4*)(src + (size_t)kr * 4096 + tx * 4);
        lds[kr][tx*4+0] = v[0]; lds[kr][tx*4+1] = v[1];
        lds[kr][tx*4+2] = v[2]; lds[kr][tx*4+3] = v[3];
    }
    __syncthreads();
    __bf16* dhi = Wt + ((l * 2 + 0) * 4096 + (size_t)n0) * 2048 + k0;
    __bf16* dlo = Wt + ((l * 2 + 1) * 4096 + (size_t)n0) * 2048 + k0;
#pragma unroll
    for (int rr = 0; rr < 4; ++rr) {
        int nr = rr * 16 + ty;
        bf16x4 ohi, olo;
#pragma unroll
        for (int j = 0; j < 4; ++j) {
            float x = lds[tx*4+j][nr];
            __bf16 h = (__bf16)x;
            ohi[j] = h;
            olo[j] = (__bf16)(x - (float)h);
        }
        *(bf16x4*)(dhi + (size_t)nr * 2048 + tx * 4) = ohi;
        *(bf16x4*)(dlo + (size_t)nr * 2048 + tx * 4) = olo;
    }
}

// plain f32 -> bf16 (hi only), 8 elems/thread, exact grid
__global__ __launch_bounds__(256) void k_cvt(const float* __restrict__ in,
                                             __bf16* __restrict__ out) {
    size_t i = ((size_t)blockIdx.x * 256 + threadIdx.x) * 8;
    f32x4 v0 = *(const f32x4*)(in + i);
    f32x4 v1 = *(const f32x4*)(in + i + 4);
    bf16x8 o;
    o[0]=(__bf16)v0[0]; o[1]=(__bf16)v0[1]; o[2]=(__bf16)v0[2]; o[3]=(__bf16)v0[3];
    o[4]=(__bf16)v1[0]; o[5]=(__bf16)v1[1]; o[6]=(__bf16)v1[2]; o[7]=(__bf16)v1[3];
    *(bf16x8*)(out + i) = o;
}

// embedding gather -> time-major [t*32+b][1024] hi/lo bf16
__global__ __launch_bounds__(256) void k_embed(const int* __restrict__ idx,
                                               const float* __restrict__ emb,
                                               __bf16* __restrict__ xhi,
                                               __bf16* __restrict__ xlo) {
    const int row = blockIdx.x;            // t*32 + b
    const int t = row >> 5, b = row & 31;
    const int id = idx[b * SEQ + t];
    const int tid = threadIdx.x;
    f32x4 v = *(const f32x4*)(emb + (size_t)id * RNN + tid * 4);
    bf16x4 hi, lo;
#pragma unroll
    for (int j = 0; j < 4; ++j) {
        __bf16 h = (__bf16)v[j];
        hi[j] = h; lo[j] = (__bf16)(v[j] - (float)h);
    }
    *(bf16x4*)(xhi + (size_t)row * RNN + tid * 4) = hi;
    *(bf16x4*)(xlo + (size_t)row * RNN + tid * 4) = lo;
}

// ---------------------------------------------------------------------------
// zx[4096][4096] = X @ Wx + bias, 3-term split bf16 MFMA (fp32-grade).
__global__ __launch_bounds__(256) void k_xgemm(const __bf16* __restrict__ xhi,
                                               const __bf16* __restrict__ xlo,
                                               const __bf16* __restrict__ Wt, // layer base
                                               const float* __restrict__ bias,
                                               float* __restrict__ zx) {
    const int tid = threadIdx.x;
    const int lane = tid & 63, w = tid >> 6;
    const int g = lane >> 4, q = lane & 15;
    const int n = blockIdx.x * 64 + w * 16 + q;
    const int m0 = blockIdx.y * 64;
    const int ko = g * 8;
    const __bf16* bh = Wt + (size_t)n * 2048;              // hi plane, k in [0,1024)
    const __bf16* bl = Wt + ((size_t)4096 + n) * 2048;     // lo plane
    f32x4 acc[4] = {{0,0,0,0},{0,0,0,0},{0,0,0,0},{0,0,0,0}};
    const __bf16 *ah[4], *al[4];
#pragma unroll
    for (int mt = 0; mt < 4; ++mt) {
        int m = m0 + mt * 16 + q;
        ah[mt] = xhi + (size_t)m * RNN;
        al[mt] = xlo + (size_t)m * RNN;
    }
#pragma unroll 2
    for (int k0 = 0; k0 < RNN; k0 += 32) {
        bf16x8 bhf = *(const bf16x8*)(bh + k0 + ko);
        bf16x8 blf = *(const bf16x8*)(bl + k0 + ko);
#pragma unroll
        for (int mt = 0; mt < 4; ++mt) {
            bf16x8 ahf = *(const bf16x8*)(ah[mt] + k0 + ko);
            bf16x8 alf = *(const bf16x8*)(al[mt] + k0 + ko);
            acc[mt] = __builtin_amdgcn_mfma_f32_16x16x32_bf16(ahf, bhf, acc[mt], 0, 0, 0);
            acc[mt] = __builtin_amdgcn_mfma_f32_16x16x32_bf16(alf, bhf, acc[mt], 0, 0, 0);
            acc[mt] = __builtin_amdgcn_mfma_f32_16x16x32_bf16(ahf, blf, acc[mt], 0, 0, 0);
        }
    }
    const float bv = bias[n];
#pragma unroll
    for (int mt = 0; mt < 4; ++mt)
#pragma unroll
        for (int r = 0; r < 4; ++r) {
            int m = m0 + mt * 16 + g * 4 + r;
            zx[(size_t)m * 4096 + n] = acc[mt][r] + bv;
        }
}

// ---------------------------------------------------------------------------
// bar layout (unsigned, in d_ws, memset 0 per launch):
// [0..7] group counters (16 blocks each)  [8] root  [9] flag1 (all-blocks)
// [10] gate counter (32 arrivals/gen)     [11] flag2 (gate-blocks arrive)
__device__ __forceinline__ void bar_all(unsigned* bar, int bk, int tid, unsigned gen) {
    __threadfence();     // release: all threads drain their stores
    __syncthreads();
    if (tid == 0) {
        unsigned v = __hip_atomic_fetch_add(&bar[bk >> 4], 1u,
                        __ATOMIC_ACQ_REL, __HIP_MEMORY_SCOPE_AGENT) + 1u;
        if (v == gen * 16u) {
            unsigned r = __hip_atomic_fetch_add(&bar[8], 1u,
                            __ATOMIC_ACQ_REL, __HIP_MEMORY_SCOPE_AGENT) + 1u;
            if (r == gen * 8u)
                __hip_atomic_store(&bar[9], gen, __ATOMIC_RELEASE,
                                   __HIP_MEMORY_SCOPE_AGENT);
        }
        while (__hip_atomic_load(&bar[9], __ATOMIC_ACQUIRE,
                                 __HIP_MEMORY_SCOPE_AGENT) < gen)
            __builtin_amdgcn_s_sleep(2);
    }
    __syncthreads();
    __threadfence();     // acquire: invalidate for fresh cross-block reads
}

__device__ __forceinline__ void bar_gates(unsigned* bar, bool arrives, int tid, unsigned gen) {
    __threadfence();
    __syncthreads();
    if (tid == 0) {
        if (arrives) {
            unsigned v = __hip_atomic_fetch_add(&bar[10], 1u,
                            __ATOMIC_ACQ_REL, __HIP_MEMORY_SCOPE_AGENT) + 1u;
            if (v == gen * 32u)
                __hip_atomic_store(&bar[11], gen, __ATOMIC_RELEASE,
                                   __HIP_MEMORY_SCOPE_AGENT);
        }
        while (__hip_atomic_load(&bar[11], __ATOMIC_ACQUIRE,
                                 __HIP_MEMORY_SCOPE_AGENT) < gen)
            __builtin_amdgcn_s_sleep(2);
    }
    __syncthreads();
    __threadfence();
}

// ---------------------------------------------------------------------------
// Persistent per-layer recurrence. 128 blocks x 256 threads, cooperative
// (for co-residency only; sync via hand-rolled barrier above).
__global__ __launch_bounds__(256, 1) void k_rnn(
        const __bf16* __restrict__ Wl,    // layer base [2][4096][2048]
        const float* __restrict__ zx,     // [SEQ*32][4096] (bias folded)
        float* __restrict__ z,            // [32][4096] scratch
        __bf16* __restrict__ hhi, __bf16* __restrict__ hlo,  // [32][1024]
        float* __restrict__ c,            // [32][1024]
        __bf16* __restrict__ xhi, __bf16* __restrict__ xlo,  // [SEQ*32][1024]
        const float* __restrict__ g5, const float* __restrict__ b5,
        unsigned* bar, unsigned gen0)
{
    __shared__ __bf16 wl[2][32768];       // 128 KB: Wh hi, lo (lane-read order)
    __shared__ float red[4][8];

    const int bk = blockIdx.x, tid = threadIdx.x;
    const int lane = tid & 63, w = tid >> 6;
    const int q = lane & 15, g = lane >> 4;
    const int mt = w & 1, nt = w >> 1;
    const int ncol = (bk << 5) + (nt << 4) + q;
    const int zr0  = (mt << 4) + (g << 2);

    // ---- stage Wh hi+lo into LDS (lane-read order) ----
    {
        const __bf16* hi_src = Wl + ((size_t)(bk << 5)) * 2048 + RNN;
        const __bf16* lo_src = Wl + ((size_t)(4096 + (bk << 5))) * 2048 + RNN;
        for (int i = tid; i < 8192; i += 256) {
            int pl = i >> 12, rem = i & 4095;
            int r = rem >> 7, cc = rem & 127;
            const __bf16* s = (pl ? lo_src : hi_src) + (size_t)r * 2048 + cc * 8;
            bf16x8 v = *(const bf16x8*)s;
            int rnt = r >> 4, rq = r & 15, kc = cc >> 2, rg = cc & 3;
            *(bf16x8*)&wl[pl][((rnt * 32 + kc) << 9) + ((rg * 16 + rq) << 3)] = v;
        }
    }

    // ---- gate-block constants (blocks 0..31) ----
    const bool is_gate = (bk < BATCH);
    f32x4 gi, bi, gj, bj, gf, bfv, go, bo, g4, b4;
    if (is_gate) {
        gi = *(const f32x4*)(g5 + 0*RNN + tid*4); bi = *(const f32x4*)(b5 + 0*RNN + tid*4);
        gj = *(const f32x4*)(g5 + 1*RNN + tid*4); bj = *(const f32x4*)(b5 + 1*RNN + tid*4);
        gf = *(const f32x4*)(g5 + 2*RNN + tid*4); bfv= *(const f32x4*)(b5 + 2*RNN + tid*4);
        go = *(const f32x4*)(g5 + 3*RNN + tid*4); bo = *(const f32x4*)(b5 + 3*RNN + tid*4);
        g4 = *(const f32x4*)(g5 + 4*RNN + tid*4); b4 = *(const f32x4*)(b5 + 4*RNN + tid*4);
    }
    const float inv = 1.f / (float)RNN;
    __syncthreads();   // LDS staged

    const __bf16* bh_base = &wl[0][(nt * 32) << 9] + (lane << 3);
    const __bf16* bl_base = &wl[1][(nt * 32) << 9] + (lane << 3);

    for (int t = 0; t < SEQ; ++t) {
        const unsigned gen = gen0 + (unsigned)t + 1u;
        // ---- phase A: z_t = zx[t] + h_{t-1} @ Wh ----
        {
            // hoist zx loads (independent of h) so L3 latency hides under MFMAs
            const float* zxp = zx + ((size_t)t * BATCH + zr0) * 4096 + ncol;
            float zv[4];
#pragma unroll
            for (int r = 0; r < 4; ++r) zv[r] = zxp[(size_t)r * 4096];

            f32x4 a0 = {0.f,0.f,0.f,0.f}, a1 = {0.f,0.f,0.f,0.f}, a2 = {0.f,0.f,0.f,0.f};
            if (t > 0) {
                const __bf16* ah = hhi + (size_t)((mt << 4) + q) * RNN;
                const __bf16* al = hlo + (size_t)((mt << 4) + q) * RNN;
#pragma unroll 4
                for (int kc = 0; kc < 32; ++kc) {
                    bf16x8 bhf = *(const bf16x8*)(bh_base + (kc << 9));
                    bf16x8 blf = *(const bf16x8*)(bl_base + (kc << 9));
                    bf16x8 ahf = *(const bf16x8*)(ah + (kc << 5) + (g << 3));
                    bf16x8 alf = *(const bf16x8*)(al + (kc << 5) + (g << 3));
                    a0 = __builtin_amdgcn_mfma_f32_16x16x32_bf16(ahf, bhf, a0, 0, 0, 0);
                    a1 = __builtin_amdgcn_mfma_f32_16x16x32_bf16(alf, bhf, a1, 0, 0, 0);
                    a2 = __builtin_amdgcn_mfma_f32_16x16x32_bf16(ahf, blf, a2, 0, 0, 0);
                }
            }
#pragma unroll
            for (int r = 0; r < 4; ++r)
                z[(size_t)(zr0 + r) * 4096 + ncol] = a0[r] + a1[r] + a2[r] + zv[r];
        }
        bar_all(bar, bk, tid, gen);    // z complete

        // ---- phase B: gates (blocks 0..31) ----
        if (is_gate) {
            const int b = bk;
            const f32x4* zr = (const f32x4*)(z + (size_t)b * 4096);
            f32x4 zi = zr[tid], zjv = zr[256 + tid], zfv = zr[512 + tid], zov = zr[768 + tid];
            float s[8];
            s[0] = zi[0]+zi[1]+zi[2]+zi[3];
            s[1] = zi[0]*zi[0]+zi[1]*zi[1]+zi[2]*zi[2]+zi[3]*zi[3];
            s[2] = zjv[0]+zjv[1]+zjv[2]+zjv[3];
            s[3] = zjv[0]*zjv[0]+zjv[1]*zjv[1]+zjv[2]*zjv[2]+zjv[3]*zjv[3];
            s[4] = zfv[0]+zfv[1]+zfv[2]+zfv[3];
            s[5] = zfv[0]*zfv[0]+zfv[1]*zfv[1]+zfv[2]*zfv[2]+zfv[3]*zfv[3];
            s[6] = zov[0]+zov[1]+zov[2]+zov[3];
            s[7] = zov[0]*zov[0]+zov[1]*zov[1]+zov[2]*zov[2]+zov[3]*zov[3];
#pragma unroll
            for (int o = 32; o; o >>= 1)
#pragma unroll
                for (int i = 0; i < 8; ++i) s[i] += __shfl_xor(s[i], o);
            if (lane == 0) {
#pragma unroll
                for (int i = 0; i < 8; ++i) red[w][i] = s[i];
            }
            __syncthreads();
            float tot[8];
#pragma unroll
            for (int i = 0; i < 8; ++i) tot[i] = red[0][i]+red[1][i]+red[2][i]+red[3][i];

            float mi = tot[0]*inv, ri = rsqrtf(tot[1]*inv - mi*mi + 1e-5f);
            float mj = tot[2]*inv, rj = rsqrtf(tot[3]*inv - mj*mj + 1e-5f);
            float mf = tot[4]*inv, rf = rsqrtf(tot[5]*inv - mf*mf + 1e-5f);
            float mo = tot[6]*inv, ro = rsqrtf(tot[7]*inv - mo*mo + 1e-5f);

            f32x4 cold = {0.f, 0.f, 0.f, 0.f};
            if (t > 0) cold = *(const f32x4*)(c + (size_t)b * RNN + tid * 4);

            f32x4 cnew, onrm;
            float cs = 0.f, cq = 0.f;
#pragma unroll
            for (int j = 0; j < 4; ++j) {
                float iv = (zi[j]-mi)*ri*gi[j] + bi[j];
                float jv = (zjv[j]-mj)*rj*gj[j] + bj[j];
                float fv = (zfv[j]-mf)*rf*gf[j] + bfv[j];
                float ov = (zov[j]-mo)*ro*go[j] + bo[j];
                float cc = cold[j] * sigm(fv + 1.0f) + sigm(iv) * tanhf(jv);
                cnew[j] = cc; onrm[j] = ov;
                cs += cc; cq += cc*cc;
            }
            *(f32x4*)(c + (size_t)b * RNN + tid * 4) = cnew;

            __syncthreads();   // protect red[] reuse
            float s2a = cs, s2b = cq;
#pragma unroll
            for (int o = 32; o; o >>= 1) { s2a += __shfl_xor(s2a, o); s2b += __shfl_xor(s2b, o); }
            if (lane == 0) { red[w][0] = s2a; red[w][1] = s2b; }
            __syncthreads();
            float mc = (red[0][0]+red[1][0]+red[2][0]+red[3][0]) * inv;
            float vc = (red[0][1]+red[1][1]+red[2][1]+red[3][1]) * inv - mc*mc;
            float rc = rsqrtf(vc + 1e-5f);

            bf16x4 hh, hl;
#pragma unroll
            for (int j = 0; j < 4; ++j) {
                float cn = (cnew[j]-mc)*rc*g4[j] + b4[j];
                float h = tanhf(cn) * sigm(onrm[j]);
                __bf16 a = (__bf16)h;
                hh[j] = a; hl[j] = (__bf16)(h - (float)a);
            }
            *(bf16x4*)(hhi + (size_t)b * RNN + tid * 4) = hh;
            *(bf16x4*)(hlo + (size_t)b * RNN + tid * 4) = hl;
            *(bf16x4*)(xhi + ((size_t)t * BATCH + b) * RNN + tid * 4) = hh;
            *(bf16x4*)(xlo + ((size_t)t * BATCH + b) * RNN + tid * 4) = hl;
        }
        bar_gates(bar, is_gate, tid, gen);   // h complete
    }
}

// ---------------------------------------------------------------------------
// logits[m][v] = sum_k h[m][k]*smw[v][k] + smb[v], m = b*128+t; plain bf16.
__global__ __launch_bounds__(256) void k_proj(const __bf16* __restrict__ xs,
                                              const __bf16* __restrict__ wv,
                                              const float* __restrict__ sb,
                                              float* __restrict__ out) {
    const int tid = threadIdx.x;
    const int lane = tid & 63, w = tid >> 6;
    const int g = lane >> 4, q = lane & 15;
    const int n = blockIdx.x * 64 + w * 16 + q;
    const int m0 = blockIdx.y * 64;
    const int ko = g * 8;
    f32x4 acc[4] = {{0,0,0,0},{0,0,0,0},{0,0,0,0},{0,0,0,0}};
    const __bf16* arow[4];
#pragma unroll
    for (int mt = 0; mt < 4; ++mt) {
        int m = m0 + mt * 16 + q;
        arow[mt] = xs + (size_t)((m & 127) * 32 + (m >> 7)) * RNN;
    }
    const __bf16* brow = wv + (size_t)n * RNN;
#pragma unroll 2
    for (int k0 = 0; k0 < RNN; k0 += 32) {
        bf16x8 bfr = *(const bf16x8*)(brow + k0 + ko);
#pragma unroll
        for (int mt = 0; mt < 4; ++mt) {
            bf16x8 afr = *(const bf16x8*)(arow[mt] + k0 + ko);
            acc[mt] = __builtin_amdgcn_mfma_f32_16x16x32_bf16(afr, bfr, acc[mt], 0, 0, 0);
        }
    }
    const float bv = sb[n];
#pragma unroll
    for (int mt = 0; mt < 4; ++mt)
#pragma unroll
        for (int r = 0; r < 4; ++r) {
            int m = m0 + mt * 16 + g * 4 + r;
            out[(size_t)m * VOCAB + n] = acc[mt][r] + bv;
        }
}

// ---------------------------------------------------------------------------
extern "C" void kernel_launch(void* const* d_in, const int* in_sizes, int n_in,
                              void* d_out, int out_size, void* d_ws, size_t ws_size,
                              hipStream_t stream) {
    const int*   input = (const int*)  d_in[0];
    const float* emb   = (const float*)d_in[1];
    const float* W     = (const float*)d_in[2];
    const float* bias  = (const float*)d_in[3];
    const float* ln_g  = (const float*)d_in[4];
    const float* ln_b  = (const float*)d_in[5];
    const float* smw   = (const float*)d_in[6];
    const float* smb   = (const float*)d_in[7];
    float* out = (float*)d_out;

    char* p = (char*)d_ws;
    auto alloc = [&](size_t bytes) { char* r = p; p += (bytes + 255) & ~(size_t)255; return r; };
    __bf16* Wt   = (__bf16*)alloc((size_t)NLAY * 2 * 4096 * 2048 * 2); // 134.2 MB
    __bf16* smwb = (__bf16*)alloc((size_t)VOCAB * RNN * 2);            // 65.5 MB
    __bf16* xhi  = (__bf16*)alloc((size_t)SEQ * BATCH * RNN * 2);      // 8.4 MB
    __bf16* xlo  = (__bf16*)alloc((size_t)SEQ * BATCH * RNN * 2);      // 8.4 MB
    float*  zx   = (float*) alloc((size_t)SEQ * BATCH * 4096 * 4);     // 67.1 MB
    float*  z    = (float*) alloc((size_t)BATCH * 4096 * 4);           // 512 KB
    __bf16* hhi  = (__bf16*)alloc((size_t)BATCH * RNN * 2);            // 64 KB
    __bf16* hlo  = (__bf16*)alloc((size_t)BATCH * RNN * 2);            // 64 KB
    float*  c    = (float*) alloc((size_t)BATCH * RNN * 4);            // 128 KB
    unsigned* bar= (unsigned*)alloc(16 * sizeof(unsigned));

    hipMemsetAsync(bar, 0, 16 * sizeof(unsigned), stream);   // reset barrier state per launch

    k_cvt_w<<<dim3(64, 32, NLAY), 256, 0, stream>>>(W, Wt);
    k_cvt<<<(VOCAB * RNN) / (8 * 256), 256, 0, stream>>>(smw, smwb);
    k_embed<<<SEQ * BATCH, 256, 0, stream>>>(input, emb, xhi, xlo);

    for (int l = 0; l < NLAY; ++l) {
        const __bf16* Wl  = Wt + (size_t)l * 2 * 4096 * 2048;
        const float*  bl  = bias + (size_t)l * 4096;
        const float*  gl  = ln_g + (size_t)l * 5 * RNN;
        const float*  bbl = ln_b + (size_t)l * 5 * RNN;
        // x-part for all timesteps (parallel GEMM, bias folded)
        k_xgemm<<<dim3(64, 64), 256, 0, stream>>>(xhi, xlo, Wl, bl, zx);
        // recurrence: cooperative (co-residency), hand-rolled barriers
        {
            const __bf16* Wl_ = Wl;
            const float*  zx_ = zx;
            float* z_ = z;
            __bf16 *hhi_ = hhi, *hlo_ = hlo;
            float* c_ = c;
            __bf16 *xhi_ = xhi, *xlo_ = xlo;
            const float *gl_ = gl, *bbl_ = bbl;
            unsigned* bar_ = bar;
            unsigned gen0 = (unsigned)(l * SEQ);
            void* args[] = {(void*)&Wl_, (void*)&zx_, (void*)&z_,
                            (void*)&hhi_, (void*)&hlo_, (void*)&c_,
                            (void*)&xhi_, (void*)&xlo_, (void*)&gl_, (void*)&bbl_,
                            (void*)&bar_, (void*)&gen0};
            hipLaunchCooperativeKernel((const void*)k_rnn,
                                       dim3(GBLK), dim3(256), args, 0, stream);
        }
    }
    // final layer output (bf16 hi) lives in xhi (time-major)
    k_proj<<<dim3(VOCAB / 64, 4096 / 64), 256, 0, stream>>>(xhi, smwb, smb, out);
}

// Round 7
// 15294.810 us; speedup vs baseline: 3.0894x; 2.4536x over previous
//
#include <hip/hip_runtime.h>
#include <hip/hip_bf16.h>

// CharRNN: embed -> 4x (LayerNorm-LSTM over T=128) -> projection to vocab.
// Round 6: fence-free step synchronization. All cross-block payloads (z, h)
// go through agent-scope relaxed atomics (sc1 -> IF$ coherence point, no
// stale per-XCD L2 copies), so barriers need NO __threadfence / L2
// writeback: per-wave vmcnt(0) drain + store-generation / poll protocol
// (root block polls one slot per thread, publishes monotonic flag).
// c lives in registers; next-layer x rows via nontemporal stores (consumed
// only by the next kernel dispatch). Wh hi+lo stays pinned in LDS.

typedef __bf16 bf16x8 __attribute__((ext_vector_type(8)));
typedef __bf16 bf16x4 __attribute__((ext_vector_type(4)));
typedef float  f32x4  __attribute__((ext_vector_type(4)));

#define VOCAB 32000
#define BATCH 32
#define SEQ   128
#define RNN   1024
#define NLAY  4
#define GBLK  128
#define ROOTBLK 127
#define AR_STRIDE 16            // dwords between arrival slots (64 B)
#define FLAG_IDX (GBLK * AR_STRIDE)

__device__ __forceinline__ float sigm(float x) { return 1.f / (1.f + __expf(-x)); }

// ---- agent-scope relaxed atomics (sc1: coherence-point, bypass stale L2) ----
__device__ __forceinline__ unsigned ald(const unsigned* p) {
    return __hip_atomic_load(p, __ATOMIC_RELAXED, __HIP_MEMORY_SCOPE_AGENT);
}
__device__ __forceinline__ void ast(unsigned* p, unsigned v) {
    __hip_atomic_store(p, v, __ATOMIC_RELAXED, __HIP_MEMORY_SCOPE_AGENT);
}
__device__ __forceinline__ unsigned long long ald64(const unsigned long long* p) {
    return __hip_atomic_load(p, __ATOMIC_RELAXED, __HIP_MEMORY_SCOPE_AGENT);
}
__device__ __forceinline__ void ast64(unsigned long long* p, unsigned long long v) {
    __hip_atomic_store(p, v, __ATOMIC_RELAXED, __HIP_MEMORY_SCOPE_AGENT);
}
__device__ __forceinline__ void astf(float* p, float v) {
    __hip_atomic_store(p, v, __ATOMIC_RELAXED, __HIP_MEMORY_SCOPE_AGENT);
}
__device__ __forceinline__ void drain_vm() {
    asm volatile("s_waitcnt vmcnt(0)" ::: "memory");
}

typedef union { unsigned long long u[2]; bf16x8 v; } U128B;
typedef union { unsigned long long u[2]; f32x4 f; }  U128F;
typedef union { unsigned long long u; bf16x4 v; }    U64B;

// ---------------------------------------------------------------------------
// W [L][2048][4096] f32 -> Wt [L][2 planes (hi,lo)][4096][2048] bf16,
// transposed to [n][k]. k 0..1023 = x-part (Wx), k 1024..2047 = h-part (Wh).
__global__ __launch_bounds__(256) void k_cvt_w(const float* __restrict__ W,
                                               __bf16* __restrict__ Wt) {
    __shared__ float lds[64][65];
    const int tid = threadIdx.x, tx = tid & 15, ty = tid >> 4;
    const int n0 = blockIdx.x * 64, k0 = blockIdx.y * 64;
    const size_t l = blockIdx.z;
    const float* src = W + (l * 2048 + (size_t)k0) * 4096 + n0;
#pragma unroll
    for (int rr = 0; rr < 4; ++rr) {
        int kr = rr * 16 + ty;
        f32x4 v = *(const f32x4*)(src + (size_t)kr * 4096 + tx * 4);
        lds[kr][tx*4+0] = v[0]; lds[kr][tx*4+1] = v[1];
        lds[kr][tx*4+2] = v[2]; lds[kr][tx*4+3] = v[3];
    }
    __syncthreads();
    __bf16* dhi = Wt + ((l * 2 + 0) * 4096 + (size_t)n0) * 2048 + k0;
    __bf16* dlo = Wt + ((l * 2 + 1) * 4096 + (size_t)n0) * 2048 + k0;
#pragma unroll
    for (int rr = 0; rr < 4; ++rr) {
        int nr = rr * 16 + ty;
        bf16x4 ohi, olo;
#pragma unroll
        for (int j = 0; j < 4; ++j) {
            float x = lds[tx*4+j][nr];
            __bf16 h = (__bf16)x;
            ohi[j] = h;
            olo[j] = (__bf16)(x - (float)h);
        }
        *(bf16x4*)(dhi + (size_t)nr * 2048 + tx * 4) = ohi;
        *(bf16x4*)(dlo + (size_t)nr * 2048 + tx * 4) = olo;
    }
}

// plain f32 -> bf16 (hi only), 8 elems/thread, exact grid
__global__ __launch_bounds__(256) void k_cvt(const float* __restrict__ in,
                                             __bf16* __restrict__ out) {
    size_t i = ((size_t)blockIdx.x * 256 + threadIdx.x) * 8;
    f32x4 v0 = *(const f32x4*)(in + i);
    f32x4 v1 = *(const f32x4*)(in + i + 4);
    bf16x8 o;
    o[0]=(__bf16)v0[0]; o[1]=(__bf16)v0[1]; o[2]=(__bf16)v0[2]; o[3]=(__bf16)v0[3];
    o[4]=(__bf16)v1[0]; o[5]=(__bf16)v1[1]; o[6]=(__bf16)v1[2]; o[7]=(__bf16)v1[3];
    *(bf16x8*)(out + i) = o;
}

// embedding gather -> time-major [t*32+b][1024] hi/lo bf16
__global__ __launch_bounds__(256) void k_embed(const int* __restrict__ idx,
                                               const float* __restrict__ emb,
                                               __bf16* __restrict__ xhi,
                                               __bf16* __restrict__ xlo) {
    const int row = blockIdx.x;            // t*32 + b
    const int t = row >> 5, b = row & 31;
    const int id = idx[b * SEQ + t];
    const int tid = threadIdx.x;
    f32x4 v = *(const f32x4*)(emb + (size_t)id * RNN + tid * 4);
    bf16x4 hi, lo;
#pragma unroll
    for (int j = 0; j < 4; ++j) {
        __bf16 h = (__bf16)v[j];
        hi[j] = h; lo[j] = (__bf16)(v[j] - (float)h);
    }
    *(bf16x4*)(xhi + (size_t)row * RNN + tid * 4) = hi;
    *(bf16x4*)(xlo + (size_t)row * RNN + tid * 4) = lo;
}

// ---------------------------------------------------------------------------
// zx[4096][4096] = X @ Wx + bias, 3-term split bf16 MFMA (fp32-grade).
__global__ __launch_bounds__(256) void k_xgemm(const __bf16* __restrict__ xhi,
                                               const __bf16* __restrict__ xlo,
                                               const __bf16* __restrict__ Wt, // layer base
                                               const float* __restrict__ bias,
                                               float* __restrict__ zx) {
    const int tid = threadIdx.x;
    const int lane = tid & 63, w = tid >> 6;
    const int g = lane >> 4, q = lane & 15;
    const int n = blockIdx.x * 64 + w * 16 + q;
    const int m0 = blockIdx.y * 64;
    const int ko = g * 8;
    const __bf16* bh = Wt + (size_t)n * 2048;              // hi plane, k in [0,1024)
    const __bf16* bl = Wt + ((size_t)4096 + n) * 2048;     // lo plane
    f32x4 acc[4] = {{0,0,0,0},{0,0,0,0},{0,0,0,0},{0,0,0,0}};
    const __bf16 *ah[4], *al[4];
#pragma unroll
    for (int mt = 0; mt < 4; ++mt) {
        int m = m0 + mt * 16 + q;
        ah[mt] = xhi + (size_t)m * RNN;
        al[mt] = xlo + (size_t)m * RNN;
    }
#pragma unroll 2
    for (int k0 = 0; k0 < RNN; k0 += 32) {
        bf16x8 bhf = *(const bf16x8*)(bh + k0 + ko);
        bf16x8 blf = *(const bf16x8*)(bl + k0 + ko);
#pragma unroll
        for (int mt = 0; mt < 4; ++mt) {
            bf16x8 ahf = *(const bf16x8*)(ah[mt] + k0 + ko);
            bf16x8 alf = *(const bf16x8*)(al[mt] + k0 + ko);
            acc[mt] = __builtin_amdgcn_mfma_f32_16x16x32_bf16(ahf, bhf, acc[mt], 0, 0, 0);
            acc[mt] = __builtin_amdgcn_mfma_f32_16x16x32_bf16(alf, bhf, acc[mt], 0, 0, 0);
            acc[mt] = __builtin_amdgcn_mfma_f32_16x16x32_bf16(ahf, blf, acc[mt], 0, 0, 0);
        }
    }
    const float bv = bias[n];
#pragma unroll
    for (int mt = 0; mt < 4; ++mt)
#pragma unroll
        for (int r = 0; r < 4; ++r) {
            int m = m0 + mt * 16 + g * 4 + r;
            zx[(size_t)m * 4096 + n] = acc[mt][r] + bv;
        }
}

// ---------------------------------------------------------------------------
// Fence-free barriers. All participating payload ops are sc1 (coherence
// point), so visibility = completion (vmcnt drain) + flag protocol.
// bar layout: slot per block at bar[bk*AR_STRIDE]; flag at bar[FLAG_IDX].
__device__ __forceinline__ void bar_all(unsigned* bar, int bk, int tid, unsigned gen) {
    drain_vm();          // each wave: its sc1 stores have reached the point
    __syncthreads();     // whole block drained
    if (bk == ROOTBLK) {
        if (tid == 0) ast(&bar[bk * AR_STRIDE], gen);
        if (tid < GBLK) {
            while (ald(&bar[tid * AR_STRIDE]) < gen) __builtin_amdgcn_s_sleep(4);
        }
        __syncthreads();
        if (tid == 0) ast(&bar[FLAG_IDX], gen);
    } else {
        if (tid == 0) {
            ast(&bar[bk * AR_STRIDE], gen);
            while (ald(&bar[FLAG_IDX]) < gen) __builtin_amdgcn_s_sleep(4);
        }
        __syncthreads();
    }
}

__device__ __forceinline__ void bar_gates(unsigned* bar, int bk, bool is_gate,
                                          int tid, unsigned gen) {
    drain_vm();
    __syncthreads();
    if (bk == ROOTBLK) {
        if (tid < BATCH) {
            while (ald(&bar[tid * AR_STRIDE]) < gen) __builtin_amdgcn_s_sleep(4);
        }
        __syncthreads();
        if (tid == 0) ast(&bar[FLAG_IDX], gen);
    } else {
        if (tid == 0) {
            if (is_gate) ast(&bar[bk * AR_STRIDE], gen);
            while (ald(&bar[FLAG_IDX]) < gen) __builtin_amdgcn_s_sleep(4);
        }
        __syncthreads();
    }
}

// ---------------------------------------------------------------------------
// Persistent per-layer recurrence. 128 blocks x 256 threads, cooperative
// (co-residency only). Wh hi+lo in LDS (lane-read order, conflict-free).
// Cross-block data strictly via sc1 atomics; c in registers.
__global__ __launch_bounds__(256, 1) void k_rnn(
        const __bf16* __restrict__ Wl,    // layer base [2][4096][2048]
        const float* __restrict__ zx,     // [SEQ*32][4096] (bias folded)
        float* __restrict__ z,            // [32][4096] scratch (sc1 only)
        __bf16* __restrict__ hhi, __bf16* __restrict__ hlo,  // [32][1024] (sc1)
        __bf16* __restrict__ xhi, __bf16* __restrict__ xlo,  // [SEQ*32][1024] (nt)
        const float* __restrict__ g5, const float* __restrict__ b5,
        unsigned* bar, unsigned gen0)
{
    __shared__ __bf16 wl[2][32768];       // 128 KB: Wh hi, lo (lane-read order)
    __shared__ float red[4][8];

    const int bk = blockIdx.x, tid = threadIdx.x;
    const int lane = tid & 63, w = tid >> 6;
    const int q = lane & 15, g = lane >> 4;
    const int mt = w & 1, nt = w >> 1;
    const int ncol = (bk << 5) + (nt << 4) + q;
    const int zr0  = (mt << 4) + (g << 2);

    // ---- stage Wh hi+lo into LDS (lane-read order) ----
    {
        const __bf16* hi_src = Wl + ((size_t)(bk << 5)) * 2048 + RNN;
        const __bf16* lo_src = Wl + ((size_t)(4096 + (bk << 5))) * 2048 + RNN;
        for (int i = tid; i < 8192; i += 256) {
            int pl = i >> 12, rem = i & 4095;
            int r = rem >> 7, cc = rem & 127;
            const __bf16* s = (pl ? lo_src : hi_src) + (size_t)r * 2048 + cc * 8;
            bf16x8 v = *(const bf16x8*)s;
            int rnt = r >> 4, rq = r & 15, kc = cc >> 2, rg = cc & 3;
            *(bf16x8*)&wl[pl][((rnt * 32 + kc) << 9) + ((rg * 16 + rq) << 3)] = v;
        }
    }

    // ---- gate-block constants (blocks 0..31) ----
    const bool is_gate = (bk < BATCH);
    f32x4 gi, bi, gj, bj, gf, bfv, go, bo, g4, b4;
    if (is_gate) {
        gi = *(const f32x4*)(g5 + 0*RNN + tid*4); bi = *(const f32x4*)(b5 + 0*RNN + tid*4);
        gj = *(const f32x4*)(g5 + 1*RNN + tid*4); bj = *(const f32x4*)(b5 + 1*RNN + tid*4);
        gf = *(const f32x4*)(g5 + 2*RNN + tid*4); bfv= *(const f32x4*)(b5 + 2*RNN + tid*4);
        go = *(const f32x4*)(g5 + 3*RNN + tid*4); bo = *(const f32x4*)(b5 + 3*RNN + tid*4);
        g4 = *(const f32x4*)(g5 + 4*RNN + tid*4); b4 = *(const f32x4*)(b5 + 4*RNN + tid*4);
    }
    const float inv = 1.f / (float)RNN;
    f32x4 creg = {0.f, 0.f, 0.f, 0.f};    // cell state lives in registers
    __syncthreads();   // LDS staged

    const __bf16* bh_base = &wl[0][(nt * 32) << 9] + (lane << 3);
    const __bf16* bl_base = &wl[1][(nt * 32) << 9] + (lane << 3);
    // h row base (u64 units) for this wave's A-fragment rows
    const unsigned long long* ahp =
        (const unsigned long long*)(hhi + (size_t)((mt << 4) + q) * RNN);
    const unsigned long long* alp =
        (const unsigned long long*)(hlo + (size_t)((mt << 4) + q) * RNN);

    for (int t = 0; t < SEQ; ++t) {
        // ---- phase A: z_t = zx[t] + h_{t-1} @ Wh ----
        {
            const float* zxp = zx + ((size_t)t * BATCH + zr0) * 4096 + ncol;
            float zv[4];
#pragma unroll
            for (int r = 0; r < 4; ++r) zv[r] = zxp[(size_t)r * 4096];

            f32x4 a0 = {0.f,0.f,0.f,0.f}, a1 = {0.f,0.f,0.f,0.f}, a2 = {0.f,0.f,0.f,0.f};
            if (t > 0) {
#pragma unroll 4
                for (int kc = 0; kc < 32; ++kc) {
                    bf16x8 bhf = *(const bf16x8*)(bh_base + (kc << 9));
                    bf16x8 blf = *(const bf16x8*)(bl_base + (kc << 9));
                    U128B uh, ul;
                    uh.u[0] = ald64(ahp + kc * 8 + g * 2);
                    uh.u[1] = ald64(ahp + kc * 8 + g * 2 + 1);
                    ul.u[0] = ald64(alp + kc * 8 + g * 2);
                    ul.u[1] = ald64(alp + kc * 8 + g * 2 + 1);
                    a0 = __builtin_amdgcn_mfma_f32_16x16x32_bf16(uh.v, bhf, a0, 0, 0, 0);
                    a1 = __builtin_amdgcn_mfma_f32_16x16x32_bf16(ul.v, bhf, a1, 0, 0, 0);
                    a2 = __builtin_amdgcn_mfma_f32_16x16x32_bf16(uh.v, blf, a2, 0, 0, 0);
                }
            }
#pragma unroll
            for (int r = 0; r < 4; ++r)
                astf(&z[(size_t)(zr0 + r) * 4096 + ncol], a0[r] + a1[r] + a2[r] + zv[r]);
        }
        bar_all(bar, bk, tid, gen0 + 2u * t + 1u);    // z visible

        // ---- phase B: gates (blocks 0..31), c in registers ----
        if (is_gate) {
            const int b = bk;
            const float* zrow = z + (size_t)b * 4096 + tid * 4;
            auto ld4 = [&](const float* p) -> f32x4 {
                U128F x;
                x.u[0] = ald64((const unsigned long long*)p);
                x.u[1] = ald64((const unsigned long long*)p + 1);
                return x.f;
            };
            f32x4 zi = ld4(zrow), zjv = ld4(zrow + 1024),
                  zfv = ld4(zrow + 2048), zov = ld4(zrow + 3072);
            float s[8];
            s[0] = zi[0]+zi[1]+zi[2]+zi[3];
            s[1] = zi[0]*zi[0]+zi[1]*zi[1]+zi[2]*zi[2]+zi[3]*zi[3];
            s[2] = zjv[0]+zjv[1]+zjv[2]+zjv[3];
            s[3] = zjv[0]*zjv[0]+zjv[1]*zjv[1]+zjv[2]*zjv[2]+zjv[3]*zjv[3];
            s[4] = zfv[0]+zfv[1]+zfv[2]+zfv[3];
            s[5] = zfv[0]*zfv[0]+zfv[1]*zfv[1]+zfv[2]*zfv[2]+zfv[3]*zfv[3];
            s[6] = zov[0]+zov[1]+zov[2]+zov[3];
            s[7] = zov[0]*zov[0]+zov[1]*zov[1]+zov[2]*zov[2]+zov[3]*zov[3];
#pragma unroll
            for (int o = 32; o; o >>= 1)
#pragma unroll
                for (int i = 0; i < 8; ++i) s[i] += __shfl_xor(s[i], o);
            if (lane == 0) {
#pragma unroll
                for (int i = 0; i < 8; ++i) red[w][i] = s[i];
            }
            __syncthreads();
            float tot[8];
#pragma unroll
            for (int i = 0; i < 8; ++i) tot[i] = red[0][i]+red[1][i]+red[2][i]+red[3][i];

            float mi = tot[0]*inv, ri = rsqrtf(tot[1]*inv - mi*mi + 1e-5f);
            float mj = tot[2]*inv, rj = rsqrtf(tot[3]*inv - mj*mj + 1e-5f);
            float mf = tot[4]*inv, rf = rsqrtf(tot[5]*inv - mf*mf + 1e-5f);
            float mo = tot[6]*inv, ro = rsqrtf(tot[7]*inv - mo*mo + 1e-5f);

            f32x4 onrm;
            float cs = 0.f, cq = 0.f;
#pragma unroll
            for (int j = 0; j < 4; ++j) {
                float iv = (zi[j]-mi)*ri*gi[j] + bi[j];
                float jv = (zjv[j]-mj)*rj*gj[j] + bj[j];
                float fv = (zfv[j]-mf)*rf*gf[j] + bfv[j];
                float ov = (zov[j]-mo)*ro*go[j] + bo[j];
                float cc = creg[j] * sigm(fv + 1.0f) + sigm(iv) * tanhf(jv);
                creg[j] = cc; onrm[j] = ov;
                cs += cc; cq += cc*cc;
            }

            __syncthreads();   // protect red[] reuse
            float s2a = cs, s2b = cq;
#pragma unroll
            for (int o = 32; o; o >>= 1) { s2a += __shfl_xor(s2a, o); s2b += __shfl_xor(s2b, o); }
            if (lane == 0) { red[w][0] = s2a; red[w][1] = s2b; }
            __syncthreads();
            float mc = (red[0][0]+red[1][0]+red[2][0]+red[3][0]) * inv;
            float vc = (red[0][1]+red[1][1]+red[2][1]+red[3][1]) * inv - mc*mc;
            float rc = rsqrtf(vc + 1e-5f);

            bf16x4 hh, hl;
#pragma unroll
            for (int j = 0; j < 4; ++j) {
                float cn = (creg[j]-mc)*rc*g4[j] + b4[j];
                float h = tanhf(cn) * sigm(onrm[j]);
                __bf16 a = (__bf16)h;
                hh[j] = a; hl[j] = (__bf16)(h - (float)a);
            }
            U64B ph, pl;
            ph.v = hh; pl.v = hl;
            ast64((unsigned long long*)&hhi[(size_t)b * RNN + tid * 4], ph.u);
            ast64((unsigned long long*)&hlo[(size_t)b * RNN + tid * 4], pl.u);
            // next-layer input rows: consumed only by the next kernel dispatch
            __builtin_nontemporal_store(hh, (bf16x4*)&xhi[((size_t)t * BATCH + b) * RNN + tid * 4]);
            __builtin_nontemporal_store(hl, (bf16x4*)&xlo[((size_t)t * BATCH + b) * RNN + tid * 4]);
        }
        bar_gates(bar, bk, is_gate, tid, gen0 + 2u * t + 2u);   // h visible
    }
}

// ---------------------------------------------------------------------------
// logits[m][v] = sum_k h[m][k]*smw[v][k] + smb[v], m = b*128+t; plain bf16.
__global__ __launch_bounds__(256) void k_proj(const __bf16* __restrict__ xs,
                                              const __bf16* __restrict__ wv,
                                              const float* __restrict__ sb,
                                              float* __restrict__ out) {
    const int tid = threadIdx.x;
    const int lane = tid & 63, w = tid >> 6;
    const int g = lane >> 4, q = lane & 15;
    const int n = blockIdx.x * 64 + w * 16 + q;
    const int m0 = blockIdx.y * 64;
    const int ko = g * 8;
    f32x4 acc[4] = {{0,0,0,0},{0,0,0,0},{0,0,0,0},{0,0,0,0}};
    const __bf16* arow[4];
#pragma unroll
    for (int mt = 0; mt < 4; ++mt) {
        int m = m0 + mt * 16 + q;
        arow[mt] = xs + (size_t)((m & 127) * 32 + (m >> 7)) * RNN;
    }
    const __bf16* brow = wv + (size_t)n * RNN;
#pragma unroll 2
    for (int k0 = 0; k0 < RNN; k0 += 32) {
        bf16x8 bfr = *(const bf16x8*)(brow + k0 + ko);
#pragma unroll
        for (int mt = 0; mt < 4; ++mt) {
            bf16x8 afr = *(const bf16x8*)(arow[mt] + k0 + ko);
            acc[mt] = __builtin_amdgcn_mfma_f32_16x16x32_bf16(afr, bfr, acc[mt], 0, 0, 0);
        }
    }
    const float bv = sb[n];
#pragma unroll
    for (int mt = 0; mt < 4; ++mt)
#pragma unroll
        for (int r = 0; r < 4; ++r) {
            int m = m0 + mt * 16 + g * 4 + r;
            out[(size_t)m * VOCAB + n] = acc[mt][r] + bv;
        }
}

// ---------------------------------------------------------------------------
extern "C" void kernel_launch(void* const* d_in, const int* in_sizes, int n_in,
                              void* d_out, int out_size, void* d_ws, size_t ws_size,
                              hipStream_t stream) {
    const int*   input = (const int*)  d_in[0];
    const float* emb   = (const float*)d_in[1];
    const float* W     = (const float*)d_in[2];
    const float* bias  = (const float*)d_in[3];
    const float* ln_g  = (const float*)d_in[4];
    const float* ln_b  = (const float*)d_in[5];
    const float* smw   = (const float*)d_in[6];
    const float* smb   = (const float*)d_in[7];
    float* out = (float*)d_out;

    char* p = (char*)d_ws;
    auto alloc = [&](size_t bytes) { char* r = p; p += (bytes + 255) & ~(size_t)255; return r; };
    __bf16* Wt   = (__bf16*)alloc((size_t)NLAY * 2 * 4096 * 2048 * 2); // 134.2 MB
    __bf16* smwb = (__bf16*)alloc((size_t)VOCAB * RNN * 2);            // 65.5 MB
    __bf16* xhi  = (__bf16*)alloc((size_t)SEQ * BATCH * RNN * 2);      // 8.4 MB
    __bf16* xlo  = (__bf16*)alloc((size_t)SEQ * BATCH * RNN * 2);      // 8.4 MB
    float*  zx   = (float*) alloc((size_t)SEQ * BATCH * 4096 * 4);     // 67.1 MB
    float*  z    = (float*) alloc((size_t)BATCH * 4096 * 4);           // 512 KB
    __bf16* hhi  = (__bf16*)alloc((size_t)BATCH * RNN * 2);            // 64 KB
    __bf16* hlo  = (__bf16*)alloc((size_t)BATCH * RNN * 2);            // 64 KB
    unsigned* bar= (unsigned*)alloc(16384);                            // slots+flag

    hipMemsetAsync(bar, 0, 16384, stream);   // reset barrier state per launch

    k_cvt_w<<<dim3(64, 32, NLAY), 256, 0, stream>>>(W, Wt);
    k_cvt<<<(VOCAB * RNN) / (8 * 256), 256, 0, stream>>>(smw, smwb);
    k_embed<<<SEQ * BATCH, 256, 0, stream>>>(input, emb, xhi, xlo);

    for (int l = 0; l < NLAY; ++l) {
        const __bf16* Wl  = Wt + (size_t)l * 2 * 4096 * 2048;
        const float*  bl  = bias + (size_t)l * 4096;
        const float*  gl  = ln_g + (size_t)l * 5 * RNN;
        const float*  bbl = ln_b + (size_t)l * 5 * RNN;
        // x-part for all timesteps (parallel GEMM, bias folded)
        k_xgemm<<<dim3(64, 64), 256, 0, stream>>>(xhi, xlo, Wl, bl, zx);
        // recurrence: cooperative (co-residency), fence-free barriers
        {
            const __bf16* Wl_ = Wl;
            const float*  zx_ = zx;
            float* z_ = z;
            __bf16 *hhi_ = hhi, *hlo_ = hlo;
            __bf16 *xhi_ = xhi, *xlo_ = xlo;
            const float *gl_ = gl, *bbl_ = bbl;
            unsigned* bar_ = bar;
            unsigned gen0 = (unsigned)(l * 2 * SEQ);
            void* args[] = {(void*)&Wl_, (void*)&zx_, (void*)&z_,
                            (void*)&hhi_, (void*)&hlo_,
                            (void*)&xhi_, (void*)&xlo_, (void*)&gl_, (void*)&bbl_,
                            (void*)&bar_, (void*)&gen0};
            hipLaunchCooperativeKernel((const void*)k_rnn,
                                       dim3(GBLK), dim3(256), args, 0, stream);
        }
    }
    // final layer output (bf16 hi) lives in xhi (time-major)
    k_proj<<<dim3(VOCAB / 64, 4096 / 64), 256, 0, stream>>>(xhi, smwb, smb, out);
}

// Round 8
// 13445.158 us; speedup vs baseline: 3.5144x; 1.1376x over previous
//
#include <hip/hip_runtime.h>
#include <hip/hip_bf16.h>

// CharRNN: embed -> 4x (LayerNorm-LSTM over T=128) -> projection to vocab.
// Round 7: (1) k_xgemm/k_proj LDS-staged in lane-read order (coalesced
// global reads, conflict-free ds_read_b128) to kill the 16B-scatter L2
// amplification; (2) k_rnn flat single-level barrier (no root/flag hop);
// (3) zx prefetch for t+1 issued right after bar1. Numerics unchanged.

typedef __bf16 bf16x8 __attribute__((ext_vector_type(8)));
typedef __bf16 bf16x4 __attribute__((ext_vector_type(4)));
typedef float  f32x4  __attribute__((ext_vector_type(4)));

#define VOCAB 32000
#define BATCH 32
#define SEQ   128
#define RNN   1024
#define NLAY  4
#define GBLK  128
#define AR_STRIDE 16            // dwords between arrival slots (64 B)

__device__ __forceinline__ float sigm(float x) { return 1.f / (1.f + __expf(-x)); }

// ---- agent-scope relaxed atomics (sc1: coherence-point, bypass stale L2) ----
__device__ __forceinline__ unsigned ald(const unsigned* p) {
    return __hip_atomic_load(p, __ATOMIC_RELAXED, __HIP_MEMORY_SCOPE_AGENT);
}
__device__ __forceinline__ void ast(unsigned* p, unsigned v) {
    __hip_atomic_store(p, v, __ATOMIC_RELAXED, __HIP_MEMORY_SCOPE_AGENT);
}
__device__ __forceinline__ unsigned long long ald64(const unsigned long long* p) {
    return __hip_atomic_load(p, __ATOMIC_RELAXED, __HIP_MEMORY_SCOPE_AGENT);
}
__device__ __forceinline__ void ast64(unsigned long long* p, unsigned long long v) {
    __hip_atomic_store(p, v, __ATOMIC_RELAXED, __HIP_MEMORY_SCOPE_AGENT);
}
__device__ __forceinline__ void astf(float* p, float v) {
    __hip_atomic_store(p, v, __ATOMIC_RELAXED, __HIP_MEMORY_SCOPE_AGENT);
}
__device__ __forceinline__ void drain_vm() {
    asm volatile("s_waitcnt vmcnt(0)" ::: "memory");
}

typedef union { unsigned long long u[2]; bf16x8 v; } U128B;
typedef union { unsigned long long u[2]; f32x4 f; }  U128F;
typedef union { unsigned long long u; bf16x4 v; }    U64B;

// ---------------------------------------------------------------------------
// W [L][2048][4096] f32 -> Wt [L][2 planes (hi,lo)][4096][2048] bf16,
// transposed to [n][k]. k 0..1023 = x-part (Wx), k 1024..2047 = h-part (Wh).
__global__ __launch_bounds__(256) void k_cvt_w(const float* __restrict__ W,
                                               __bf16* __restrict__ Wt) {
    __shared__ float lds[64][65];
    const int tid = threadIdx.x, tx = tid & 15, ty = tid >> 4;
    const int n0 = blockIdx.x * 64, k0 = blockIdx.y * 64;
    const size_t l = blockIdx.z;
    const float* src = W + (l * 2048 + (size_t)k0) * 4096 + n0;
#pragma unroll
    for (int rr = 0; rr < 4; ++rr) {
        int kr = rr * 16 + ty;
        f32x4 v = *(const f32x4*)(src + (size_t)kr * 4096 + tx * 4);
        lds[kr][tx*4+0] = v[0]; lds[kr][tx*4+1] = v[1];
        lds[kr][tx*4+2] = v[2]; lds[kr][tx*4+3] = v[3];
    }
    __syncthreads();
    __bf16* dhi = Wt + ((l * 2 + 0) * 4096 + (size_t)n0) * 2048 + k0;
    __bf16* dlo = Wt + ((l * 2 + 1) * 4096 + (size_t)n0) * 2048 + k0;
#pragma unroll
    for (int rr = 0; rr < 4; ++rr) {
        int nr = rr * 16 + ty;
        bf16x4 ohi, olo;
#pragma unroll
        for (int j = 0; j < 4; ++j) {
            float x = lds[tx*4+j][nr];
            __bf16 h = (__bf16)x;
            ohi[j] = h;
            olo[j] = (__bf16)(x - (float)h);
        }
        *(bf16x4*)(dhi + (size_t)nr * 2048 + tx * 4) = ohi;
        *(bf16x4*)(dlo + (size_t)nr * 2048 + tx * 4) = olo;
    }
}

// plain f32 -> bf16 (hi only), 8 elems/thread, exact grid
__global__ __launch_bounds__(256) void k_cvt(const float* __restrict__ in,
                                             __bf16* __restrict__ out) {
    size_t i = ((size_t)blockIdx.x * 256 + threadIdx.x) * 8;
    f32x4 v0 = *(const f32x4*)(in + i);
    f32x4 v1 = *(const f32x4*)(in + i + 4);
    bf16x8 o;
    o[0]=(__bf16)v0[0]; o[1]=(__bf16)v0[1]; o[2]=(__bf16)v0[2]; o[3]=(__bf16)v0[3];
    o[4]=(__bf16)v1[0]; o[5]=(__bf16)v1[1]; o[6]=(__bf16)v1[2]; o[7]=(__bf16)v1[3];
    *(bf16x8*)(out + i) = o;
}

// embedding gather -> time-major [t*32+b][1024] hi/lo bf16
__global__ __launch_bounds__(256) void k_embed(const int* __restrict__ idx,
                                               const float* __restrict__ emb,
                                               __bf16* __restrict__ xhi,
                                               __bf16* __restrict__ xlo) {
    const int row = blockIdx.x;            // t*32 + b
    const int t = row >> 5, b = row & 31;
    const int id = idx[b * SEQ + t];
    const int tid = threadIdx.x;
    f32x4 v = *(const f32x4*)(emb + (size_t)id * RNN + tid * 4);
    bf16x4 hi, lo;
#pragma unroll
    for (int j = 0; j < 4; ++j) {
        __bf16 h = (__bf16)v[j];
        hi[j] = h; lo[j] = (__bf16)(v[j] - (float)h);
    }
    *(bf16x4*)(xhi + (size_t)row * RNN + tid * 4) = hi;
    *(bf16x4*)(xlo + (size_t)row * RNN + tid * 4) = lo;
}

// ---------------------------------------------------------------------------
// zx[4096][4096] = X @ Wx + bias, 3-term split bf16 MFMA, LDS-staged.
// BK=128; A/B tiles staged in lane-read order (write: [mt][kc][rg*16+rq]
// where rg=cc&3, rq=r&15; read: [mt][kc][lane] -> conflict-free b128).
__global__ __launch_bounds__(256) void k_xgemm(const __bf16* __restrict__ xhi,
                                               const __bf16* __restrict__ xlo,
                                               const __bf16* __restrict__ Wt, // layer base
                                               const float* __restrict__ bias,
                                               float* __restrict__ zx) {
    __shared__ __bf16 Aim[2][4][4][512];   // 32 KB (hi/lo planes)
    __shared__ __bf16 Bim[2][4][4][512];   // 32 KB
    const int tid = threadIdx.x;
    const int lane = tid & 63, w = tid >> 6;
    const int g = lane >> 4, q = lane & 15;
    const int n0 = blockIdx.x * 64, m0 = blockIdx.y * 64;
    f32x4 acc[4] = {{0,0,0,0},{0,0,0,0},{0,0,0,0},{0,0,0,0}};

    for (int ch = 0; ch < 8; ++ch) {       // 8 chunks of K=128
        __syncthreads();                   // previous compute done
        for (int i = tid; i < 2048; i += 256) {   // stage A (both planes)
            int pl = i >> 10, rem = i & 1023;
            int r = rem >> 4, cc = rem & 15;
            const __bf16* s = (pl ? xlo : xhi) + (size_t)(m0 + r) * RNN + ch * 128 + cc * 8;
            bf16x8 v = *(const bf16x8*)s;
            *(bf16x8*)&Aim[pl][r >> 4][cc >> 2][(((cc & 3) << 4) + (r & 15)) << 3] = v;
        }
        for (int i = tid; i < 2048; i += 256) {   // stage B (both planes)
            int pl = i >> 10, rem = i & 1023;
            int r = rem >> 4, cc = rem & 15;
            const __bf16* s = Wt + ((size_t)(pl ? 4096 : 0) + n0 + r) * 2048 + ch * 128 + cc * 8;
            bf16x8 v = *(const bf16x8*)s;
            *(bf16x8*)&Bim[pl][r >> 4][cc >> 2][(((cc & 3) << 4) + (r & 15)) << 3] = v;
        }
        __syncthreads();
#pragma unroll
        for (int kc = 0; kc < 4; ++kc) {
            bf16x8 bhf = *(const bf16x8*)&Bim[0][w][kc][lane << 3];
            bf16x8 blf = *(const bf16x8*)&Bim[1][w][kc][lane << 3];
#pragma unroll
            for (int mt = 0; mt < 4; ++mt) {
                bf16x8 ahf = *(const bf16x8*)&Aim[0][mt][kc][lane << 3];
                bf16x8 alf = *(const bf16x8*)&Aim[1][mt][kc][lane << 3];
                acc[mt] = __builtin_amdgcn_mfma_f32_16x16x32_bf16(ahf, bhf, acc[mt], 0, 0, 0);
                acc[mt] = __builtin_amdgcn_mfma_f32_16x16x32_bf16(alf, bhf, acc[mt], 0, 0, 0);
                acc[mt] = __builtin_amdgcn_mfma_f32_16x16x32_bf16(ahf, blf, acc[mt], 0, 0, 0);
            }
        }
    }
    const int n = n0 + w * 16 + q;
    const float bv = bias[n];
#pragma unroll
    for (int mt = 0; mt < 4; ++mt)
#pragma unroll
        for (int r = 0; r < 4; ++r) {
            int m = m0 + mt * 16 + g * 4 + r;
            zx[(size_t)m * 4096 + n] = acc[mt][r] + bv;
        }
}

// ---------------------------------------------------------------------------
// Flat single-level fence-free barriers (sc1 payloads; visibility =
// vmcnt drain + slot store/poll; slots padded 64 B; one slot per block).
__device__ __forceinline__ void bar_all(unsigned* slots, int bk, int tid, unsigned gen) {
    drain_vm();
    __syncthreads();
    if (tid == 0) ast(&slots[bk * AR_STRIDE], gen);
    if (tid < GBLK) {
        while (ald(&slots[tid * AR_STRIDE]) < gen) __builtin_amdgcn_s_sleep(1);
    }
    __syncthreads();
}
__device__ __forceinline__ void bar_gate(unsigned* slots, int bk, bool arrive,
                                         int tid, unsigned gen) {
    drain_vm();
    __syncthreads();
    if (arrive && tid == 0) ast(&slots[bk * AR_STRIDE], gen);
    if (tid < BATCH) {
        while (ald(&slots[tid * AR_STRIDE]) < gen) __builtin_amdgcn_s_sleep(1);
    }
    __syncthreads();
}

// ---------------------------------------------------------------------------
// Persistent per-layer recurrence. 128 blocks x 256 threads, cooperative
// (co-residency only). Wh hi+lo in LDS (lane-read order, conflict-free).
// Cross-block data strictly via sc1 atomics; c in registers; zx prefetched.
__global__ __launch_bounds__(256, 1) void k_rnn(
        const __bf16* __restrict__ Wl,    // layer base [2][4096][2048]
        const float* __restrict__ zx,     // [SEQ*32][4096] (bias folded)
        float* __restrict__ z,            // [32][4096] scratch (sc1 only)
        __bf16* __restrict__ hhi, __bf16* __restrict__ hlo,  // [32][1024] (sc1)
        __bf16* __restrict__ xhi, __bf16* __restrict__ xlo,  // [SEQ*32][1024] (nt)
        const float* __restrict__ g5, const float* __restrict__ b5,
        unsigned* bar, unsigned gen0)
{
    __shared__ __bf16 wl[2][32768];       // 128 KB: Wh hi, lo (lane-read order)
    __shared__ float red[4][8];
    unsigned* bar2 = bar + GBLK * AR_STRIDE;

    const int bk = blockIdx.x, tid = threadIdx.x;
    const int lane = tid & 63, w = tid >> 6;
    const int q = lane & 15, g = lane >> 4;
    const int mt = w & 1, nt = w >> 1;
    const int ncol = (bk << 5) + (nt << 4) + q;
    const int zr0  = (mt << 4) + (g << 2);

    // ---- stage Wh hi+lo into LDS (lane-read order) ----
    {
        const __bf16* hi_src = Wl + ((size_t)(bk << 5)) * 2048 + RNN;
        const __bf16* lo_src = Wl + ((size_t)(4096 + (bk << 5))) * 2048 + RNN;
        for (int i = tid; i < 8192; i += 256) {
            int pl = i >> 12, rem = i & 4095;
            int r = rem >> 7, cc = rem & 127;
            const __bf16* s = (pl ? lo_src : hi_src) + (size_t)r * 2048 + cc * 8;
            bf16x8 v = *(const bf16x8*)s;
            int rnt = r >> 4, rq = r & 15, kc = cc >> 2, rg = cc & 3;
            *(bf16x8*)&wl[pl][((rnt * 32 + kc) << 9) + ((rg * 16 + rq) << 3)] = v;
        }
    }

    // ---- gate-block constants (blocks 0..31) ----
    const bool is_gate = (bk < BATCH);
    f32x4 gi, bi, gj, bj, gf, bfv, go, bo, g4, b4;
    if (is_gate) {
        gi = *(const f32x4*)(g5 + 0*RNN + tid*4); bi = *(const f32x4*)(b5 + 0*RNN + tid*4);
        gj = *(const f32x4*)(g5 + 1*RNN + tid*4); bj = *(const f32x4*)(b5 + 1*RNN + tid*4);
        gf = *(const f32x4*)(g5 + 2*RNN + tid*4); bfv= *(const f32x4*)(b5 + 2*RNN + tid*4);
        go = *(const f32x4*)(g5 + 3*RNN + tid*4); bo = *(const f32x4*)(b5 + 3*RNN + tid*4);
        g4 = *(const f32x4*)(g5 + 4*RNN + tid*4); b4 = *(const f32x4*)(b5 + 4*RNN + tid*4);
    }
    const float inv = 1.f / (float)RNN;
    f32x4 creg = {0.f, 0.f, 0.f, 0.f};    // cell state lives in registers
    __syncthreads();   // LDS staged

    const __bf16* bh_base = &wl[0][(nt * 32) << 9] + (lane << 3);
    const __bf16* bl_base = &wl[1][(nt * 32) << 9] + (lane << 3);
    const unsigned long long* ahp =
        (const unsigned long long*)(hhi + (size_t)((mt << 4) + q) * RNN);
    const unsigned long long* alp =
        (const unsigned long long*)(hlo + (size_t)((mt << 4) + q) * RNN);

    // zx prefetch (t = 0)
    float zv[4];
    {
        const float* zxp = zx + ((size_t)zr0) * 4096 + ncol;
#pragma unroll
        for (int r = 0; r < 4; ++r) zv[r] = zxp[(size_t)r * 4096];
    }

    for (int t = 0; t < SEQ; ++t) {
        const unsigned gen = gen0 + (unsigned)t + 1u;
        // ---- phase A: z_t = zx[t] + h_{t-1} @ Wh ----
        {
            f32x4 a0 = {0.f,0.f,0.f,0.f}, a1 = {0.f,0.f,0.f,0.f}, a2 = {0.f,0.f,0.f,0.f};
            if (t > 0) {
#pragma unroll 4
                for (int kc = 0; kc < 32; ++kc) {
                    bf16x8 bhf = *(const bf16x8*)(bh_base + (kc << 9));
                    bf16x8 blf = *(const bf16x8*)(bl_base + (kc << 9));
                    U128B uh, ul;
                    uh.u[0] = ald64(ahp + kc * 8 + g * 2);
                    uh.u[1] = ald64(ahp + kc * 8 + g * 2 + 1);
                    ul.u[0] = ald64(alp + kc * 8 + g * 2);
                    ul.u[1] = ald64(alp + kc * 8 + g * 2 + 1);
                    a0 = __builtin_amdgcn_mfma_f32_16x16x32_bf16(uh.v, bhf, a0, 0, 0, 0);
                    a1 = __builtin_amdgcn_mfma_f32_16x16x32_bf16(ul.v, bhf, a1, 0, 0, 0);
                    a2 = __builtin_amdgcn_mfma_f32_16x16x32_bf16(uh.v, blf, a2, 0, 0, 0);
                }
            }
#pragma unroll
            for (int r = 0; r < 4; ++r)
                astf(&z[(size_t)(zr0 + r) * 4096 + ncol], a0[r] + a1[r] + a2[r] + zv[r]);
        }
        bar_all(bar, bk, tid, gen);    // z visible

        // ---- prefetch zx for t+1 (constant data; hides under phase B/spin) ----
        float zvn[4] = {0.f, 0.f, 0.f, 0.f};
        if (t + 1 < SEQ) {
            const float* zxp = zx + ((size_t)(t + 1) * BATCH + zr0) * 4096 + ncol;
#pragma unroll
            for (int r = 0; r < 4; ++r) zvn[r] = zxp[(size_t)r * 4096];
        }

        // ---- phase B: gates (blocks 0..31), c in registers ----
        if (is_gate) {
            const int b = bk;
            const float* zrow = z + (size_t)b * 4096 + tid * 4;
            auto ld4 = [&](const float* p) -> f32x4 {
                U128F x;
                x.u[0] = ald64((const unsigned long long*)p);
                x.u[1] = ald64((const unsigned long long*)p + 1);
                return x.f;
            };
            f32x4 zi = ld4(zrow), zjv = ld4(zrow + 1024),
                  zfv = ld4(zrow + 2048), zov = ld4(zrow + 3072);
            float s[8];
            s[0] = zi[0]+zi[1]+zi[2]+zi[3];
            s[1] = zi[0]*zi[0]+zi[1]*zi[1]+zi[2]*zi[2]+zi[3]*zi[3];
            s[2] = zjv[0]+zjv[1]+zjv[2]+zjv[3];
            s[3] = zjv[0]*zjv[0]+zjv[1]*zjv[1]+zjv[2]*zjv[2]+zjv[3]*zjv[3];
            s[4] = zfv[0]+zfv[1]+zfv[2]+zfv[3];
            s[5] = zfv[0]*zfv[0]+zfv[1]*zfv[1]+zfv[2]*zfv[2]+zfv[3]*zfv[3];
            s[6] = zov[0]+zov[1]+zov[2]+zov[3];
            s[7] = zov[0]*zov[0]+zov[1]*zov[1]+zov[2]*zov[2]+zov[3]*zov[3];
#pragma unroll
            for (int o = 32; o; o >>= 1)
#pragma unroll
                for (int i = 0; i < 8; ++i) s[i] += __shfl_xor(s[i], o);
            if (lane == 0) {
#pragma unroll
                for (int i = 0; i < 8; ++i) red[w][i] = s[i];
            }
            __syncthreads();
            float tot[8];
#pragma unroll
            for (int i = 0; i < 8; ++i) tot[i] = red[0][i]+red[1][i]+red[2][i]+red[3][i];

            float mi = tot[0]*inv, ri = rsqrtf(tot[1]*inv - mi*mi + 1e-5f);
            float mj = tot[2]*inv, rj = rsqrtf(tot[3]*inv - mj*mj + 1e-5f);
            float mf = tot[4]*inv, rf = rsqrtf(tot[5]*inv - mf*mf + 1e-5f);
            float mo = tot[6]*inv, ro = rsqrtf(tot[7]*inv - mo*mo + 1e-5f);

            f32x4 onrm;
            float cs = 0.f, cq = 0.f;
#pragma unroll
            for (int j = 0; j < 4; ++j) {
                float iv = (zi[j]-mi)*ri*gi[j] + bi[j];
                float jv = (zjv[j]-mj)*rj*gj[j] + bj[j];
                float fv = (zfv[j]-mf)*rf*gf[j] + bfv[j];
                float ov = (zov[j]-mo)*ro*go[j] + bo[j];
                float cc = creg[j] * sigm(fv + 1.0f) + sigm(iv) * tanhf(jv);
                creg[j] = cc; onrm[j] = ov;
                cs += cc; cq += cc*cc;
            }

            __syncthreads();   // protect red[] reuse
            float s2a = cs, s2b = cq;
#pragma unroll
            for (int o = 32; o; o >>= 1) { s2a += __shfl_xor(s2a, o); s2b += __shfl_xor(s2b, o); }
            if (lane == 0) { red[w][0] = s2a; red[w][1] = s2b; }
            __syncthreads();
            float mc = (red[0][0]+red[1][0]+red[2][0]+red[3][0]) * inv;
            float vc = (red[0][1]+red[1][1]+red[2][1]+red[3][1]) * inv - mc*mc;
            float rc = rsqrtf(vc + 1e-5f);

            bf16x4 hh, hl;
#pragma unroll
            for (int j = 0; j < 4; ++j) {
                float cn = (creg[j]-mc)*rc*g4[j] + b4[j];
                float h = tanhf(cn) * sigm(onrm[j]);
                __bf16 a = (__bf16)h;
                hh[j] = a; hl[j] = (__bf16)(h - (float)a);
            }
            U64B ph, pl;
            ph.v = hh; pl.v = hl;
            ast64((unsigned long long*)&hhi[(size_t)b * RNN + tid * 4], ph.u);
            ast64((unsigned long long*)&hlo[(size_t)b * RNN + tid * 4], pl.u);
            __builtin_nontemporal_store(hh, (bf16x4*)&xhi[((size_t)t * BATCH + b) * RNN + tid * 4]);
            __builtin_nontemporal_store(hl, (bf16x4*)&xlo[((size_t)t * BATCH + b) * RNN + tid * 4]);
        }
        bar_gate(bar2, bk, is_gate, tid, gen);   // h visible
#pragma unroll
        for (int r = 0; r < 4; ++r) zv[r] = zvn[r];
    }
}

// ---------------------------------------------------------------------------
// logits[m][v] = sum_k h[m][k]*smw[v][k] + smb[v], m = b*128+t; plain bf16,
// LDS-staged (BK=256). Source row in time-major buffer = (m&127)*32+(m>>7).
__global__ __launch_bounds__(256) void k_proj(const __bf16* __restrict__ xs,
                                              const __bf16* __restrict__ wv,
                                              const float* __restrict__ sb,
                                              float* __restrict__ out) {
    __shared__ __bf16 Aim[4][8][512];      // 32 KB
    __shared__ __bf16 Bim[4][8][512];      // 32 KB
    const int tid = threadIdx.x;
    const int lane = tid & 63, w = tid >> 6;
    const int g = lane >> 4, q = lane & 15;
    const int n0 = blockIdx.x * 64, m0 = blockIdx.y * 64;
    f32x4 acc[4] = {{0,0,0,0},{0,0,0,0},{0,0,0,0},{0,0,0,0}};

    for (int ch = 0; ch < 4; ++ch) {       // 4 chunks of K=256
        __syncthreads();
        for (int i = tid; i < 2048; i += 256) {   // stage A
            int r = i >> 5, cc = i & 31;
            int m = m0 + r;
            const __bf16* s = xs + (size_t)((m & 127) * 32 + (m >> 7)) * RNN + ch * 256 + cc * 8;
            bf16x8 v = *(const bf16x8*)s;
            *(bf16x8*)&Aim[r >> 4][cc >> 2][(((cc & 3) << 4) + (r & 15)) << 3] = v;
        }
        for (int i = tid; i < 2048; i += 256) {   // stage B
            int r = i >> 5, cc = i & 31;
            const __bf16* s = wv + (size_t)(n0 + r) * RNN + ch * 256 + cc * 8;
            bf16x8 v = *(const bf16x8*)s;
            *(bf16x8*)&Bim[r >> 4][cc >> 2][(((cc & 3) << 4) + (r & 15)) << 3] = v;
        }
        __syncthreads();
#pragma unroll
        for (int kc = 0; kc < 8; ++kc) {
            bf16x8 bfr = *(const bf16x8*)&Bim[w][kc][lane << 3];
#pragma unroll
            for (int mt = 0; mt < 4; ++mt) {
                bf16x8 afr = *(const bf16x8*)&Aim[mt][kc][lane << 3];
                acc[mt] = __builtin_amdgcn_mfma_f32_16x16x32_bf16(afr, bfr, acc[mt], 0, 0, 0);
            }
        }
    }
    const int n = n0 + w * 16 + q;
    const float bv = sb[n];
#pragma unroll
    for (int mt = 0; mt < 4; ++mt)
#pragma unroll
        for (int r = 0; r < 4; ++r) {
            int m = m0 + mt * 16 + g * 4 + r;
            __builtin_nontemporal_store(acc[mt][r] + bv, &out[(size_t)m * VOCAB + n]);
        }
}

// ---------------------------------------------------------------------------
extern "C" void kernel_launch(void* const* d_in, const int* in_sizes, int n_in,
                              void* d_out, int out_size, void* d_ws, size_t ws_size,
                              hipStream_t stream) {
    const int*   input = (const int*)  d_in[0];
    const float* emb   = (const float*)d_in[1];
    const float* W     = (const float*)d_in[2];
    const float* bias  = (const float*)d_in[3];
    const float* ln_g  = (const float*)d_in[4];
    const float* ln_b  = (const float*)d_in[5];
    const float* smw   = (const float*)d_in[6];
    const float* smb   = (const float*)d_in[7];
    float* out = (float*)d_out;

    char* p = (char*)d_ws;
    auto alloc = [&](size_t bytes) { char* r = p; p += (bytes + 255) & ~(size_t)255; return r; };
    __bf16* Wt   = (__bf16*)alloc((size_t)NLAY * 2 * 4096 * 2048 * 2); // 134.2 MB
    __bf16* smwb = (__bf16*)alloc((size_t)VOCAB * RNN * 2);            // 65.5 MB
    __bf16* xhi  = (__bf16*)alloc((size_t)SEQ * BATCH * RNN * 2);      // 8.4 MB
    __bf16* xlo  = (__bf16*)alloc((size_t)SEQ * BATCH * RNN * 2);      // 8.4 MB
    float*  zx   = (float*) alloc((size_t)SEQ * BATCH * 4096 * 4);     // 67.1 MB
    float*  z    = (float*) alloc((size_t)BATCH * 4096 * 4);           // 512 KB
    __bf16* hhi  = (__bf16*)alloc((size_t)BATCH * RNN * 2);            // 64 KB
    __bf16* hlo  = (__bf16*)alloc((size_t)BATCH * RNN * 2);            // 64 KB
    unsigned* bar= (unsigned*)alloc(2 * GBLK * AR_STRIDE * 4);         // 2 slot arrays

    hipMemsetAsync(bar, 0, 2 * GBLK * AR_STRIDE * 4, stream);

    k_cvt_w<<<dim3(64, 32, NLAY), 256, 0, stream>>>(W, Wt);
    k_cvt<<<(VOCAB * RNN) / (8 * 256), 256, 0, stream>>>(smw, smwb);
    k_embed<<<SEQ * BATCH, 256, 0, stream>>>(input, emb, xhi, xlo);

    for (int l = 0; l < NLAY; ++l) {
        const __bf16* Wl  = Wt + (size_t)l * 2 * 4096 * 2048;
        const float*  bl  = bias + (size_t)l * 4096;
        const float*  gl  = ln_g + (size_t)l * 5 * RNN;
        const float*  bbl = ln_b + (size_t)l * 5 * RNN;
        k_xgemm<<<dim3(64, 64), 256, 0, stream>>>(xhi, xlo, Wl, bl, zx);
        {
            const __bf16* Wl_ = Wl;
            const float*  zx_ = zx;
            float* z_ = z;
            __bf16 *hhi_ = hhi, *hlo_ = hlo;
            __bf16 *xhi_ = xhi, *xlo_ = xlo;
            const float *gl_ = gl, *bbl_ = bbl;
            unsigned* bar_ = bar;
            unsigned gen0 = (unsigned)(l * SEQ);
            void* args[] = {(void*)&Wl_, (void*)&zx_, (void*)&z_,
                            (void*)&hhi_, (void*)&hlo_,
                            (void*)&xhi_, (void*)&xlo_, (void*)&gl_, (void*)&bbl_,
                            (void*)&bar_, (void*)&gen0};
            hipLaunchCooperativeKernel((const void*)k_rnn,
                                       dim3(GBLK), dim3(256), args, 0, stream);
        }
    }
    // final layer output (bf16 hi) lives in xhi (time-major)
    k_proj<<<dim3(VOCAB / 64, 4096 / 64), 256, 0, stream>>>(xhi, smwb, smb, out);
}

// Round 9
// 8190.353 us; speedup vs baseline: 5.7692x; 1.6416x over previous
//
#include <hip/hip_runtime.h>
#include <hip/hip_bf16.h>

// CharRNN: embed -> 4x (LayerNorm-LSTM over T=128) -> projection to vocab.
// Round 8: h-broadcast fix. h lives only in the time-indexed xhi/xlo buffers
// (written once per step via sc1 stores); readers use NORMAL 16B vector
// loads -- safe because each address is read exactly once per dispatch and
// dispatch boundaries invalidate per-XCD L2 (empirically proven by zx path).
// K-split wave geometry (mt x khalf) removes intra-block duplicate h reads;
// partial accumulators exchanged via 4KB LDS. 32MB/step coherence traffic
// -> 16MB in 4x fewer, non-atomic instructions.

typedef __bf16 bf16x8 __attribute__((ext_vector_type(8)));
typedef __bf16 bf16x4 __attribute__((ext_vector_type(4)));
typedef float  f32x4  __attribute__((ext_vector_type(4)));

#define VOCAB 32000
#define BATCH 32
#define SEQ   128
#define RNN   1024
#define NLAY  4
#define GBLK  128
#define AR_STRIDE 16            // dwords between arrival slots (64 B)

__device__ __forceinline__ float sigm(float x) { return 1.f / (1.f + __expf(-x)); }

// ---- agent-scope relaxed atomics (sc1: coherence-point, bypass stale L2) ----
__device__ __forceinline__ unsigned ald(const unsigned* p) {
    return __hip_atomic_load(p, __ATOMIC_RELAXED, __HIP_MEMORY_SCOPE_AGENT);
}
__device__ __forceinline__ void ast(unsigned* p, unsigned v) {
    __hip_atomic_store(p, v, __ATOMIC_RELAXED, __HIP_MEMORY_SCOPE_AGENT);
}
__device__ __forceinline__ unsigned long long ald64(const unsigned long long* p) {
    return __hip_atomic_load(p, __ATOMIC_RELAXED, __HIP_MEMORY_SCOPE_AGENT);
}
__device__ __forceinline__ void ast64(unsigned long long* p, unsigned long long v) {
    __hip_atomic_store(p, v, __ATOMIC_RELAXED, __HIP_MEMORY_SCOPE_AGENT);
}
__device__ __forceinline__ void astf(float* p, float v) {
    __hip_atomic_store(p, v, __ATOMIC_RELAXED, __HIP_MEMORY_SCOPE_AGENT);
}
__device__ __forceinline__ void drain_vm() {
    asm volatile("s_waitcnt vmcnt(0)" ::: "memory");
}

typedef union { unsigned long long u[2]; f32x4 f; }  U128F;
typedef union { unsigned long long u; bf16x4 v; }    U64B;

// ---------------------------------------------------------------------------
// W [L][2048][4096] f32 -> Wt [L][2 planes (hi,lo)][4096][2048] bf16,
// transposed to [n][k]. k 0..1023 = x-part (Wx), k 1024..2047 = h-part (Wh).
__global__ __launch_bounds__(256) void k_cvt_w(const float* __restrict__ W,
                                               __bf16* __restrict__ Wt) {
    __shared__ float lds[64][65];
    const int tid = threadIdx.x, tx = tid & 15, ty = tid >> 4;
    const int n0 = blockIdx.x * 64, k0 = blockIdx.y * 64;
    const size_t l = blockIdx.z;
    const float* src = W + (l * 2048 + (size_t)k0) * 4096 + n0;
#pragma unroll
    for (int rr = 0; rr < 4; ++rr) {
        int kr = rr * 16 + ty;
        f32x4 v = *(const f32x4*)(src + (size_t)kr * 4096 + tx * 4);
        lds[kr][tx*4+0] = v[0]; lds[kr][tx*4+1] = v[1];
        lds[kr][tx*4+2] = v[2]; lds[kr][tx*4+3] = v[3];
    }
    __syncthreads();
    __bf16* dhi = Wt + ((l * 2 + 0) * 4096 + (size_t)n0) * 2048 + k0;
    __bf16* dlo = Wt + ((l * 2 + 1) * 4096 + (size_t)n0) * 2048 + k0;
#pragma unroll
    for (int rr = 0; rr < 4; ++rr) {
        int nr = rr * 16 + ty;
        bf16x4 ohi, olo;
#pragma unroll
        for (int j = 0; j < 4; ++j) {
            float x = lds[tx*4+j][nr];
            __bf16 h = (__bf16)x;
            ohi[j] = h;
            olo[j] = (__bf16)(x - (float)h);
        }
        *(bf16x4*)(dhi + (size_t)nr * 2048 + tx * 4) = ohi;
        *(bf16x4*)(dlo + (size_t)nr * 2048 + tx * 4) = olo;
    }
}

// plain f32 -> bf16 (hi only), 8 elems/thread, exact grid
__global__ __launch_bounds__(256) void k_cvt(const float* __restrict__ in,
                                             __bf16* __restrict__ out) {
    size_t i = ((size_t)blockIdx.x * 256 + threadIdx.x) * 8;
    f32x4 v0 = *(const f32x4*)(in + i);
    f32x4 v1 = *(const f32x4*)(in + i + 4);
    bf16x8 o;
    o[0]=(__bf16)v0[0]; o[1]=(__bf16)v0[1]; o[2]=(__bf16)v0[2]; o[3]=(__bf16)v0[3];
    o[4]=(__bf16)v1[0]; o[5]=(__bf16)v1[1]; o[6]=(__bf16)v1[2]; o[7]=(__bf16)v1[3];
    *(bf16x8*)(out + i) = o;
}

// embedding gather -> time-major [t*32+b][1024] hi/lo bf16
__global__ __launch_bounds__(256) void k_embed(const int* __restrict__ idx,
                                               const float* __restrict__ emb,
                                               __bf16* __restrict__ xhi,
                                               __bf16* __restrict__ xlo) {
    const int row = blockIdx.x;            // t*32 + b
    const int t = row >> 5, b = row & 31;
    const int id = idx[b * SEQ + t];
    const int tid = threadIdx.x;
    f32x4 v = *(const f32x4*)(emb + (size_t)id * RNN + tid * 4);
    bf16x4 hi, lo;
#pragma unroll
    for (int j = 0; j < 4; ++j) {
        __bf16 h = (__bf16)v[j];
        hi[j] = h; lo[j] = (__bf16)(v[j] - (float)h);
    }
    *(bf16x4*)(xhi + (size_t)row * RNN + tid * 4) = hi;
    *(bf16x4*)(xlo + (size_t)row * RNN + tid * 4) = lo;
}

// ---------------------------------------------------------------------------
// zx[4096][4096] = X @ Wx + bias, 3-term split bf16 MFMA, LDS-staged.
__global__ __launch_bounds__(256) void k_xgemm(const __bf16* __restrict__ xhi,
                                               const __bf16* __restrict__ xlo,
                                               const __bf16* __restrict__ Wt, // layer base
                                               const float* __restrict__ bias,
                                               float* __restrict__ zx) {
    __shared__ __bf16 Aim[2][4][4][512];   // 32 KB (hi/lo planes)
    __shared__ __bf16 Bim[2][4][4][512];   // 32 KB
    const int tid = threadIdx.x;
    const int lane = tid & 63, w = tid >> 6;
    const int g = lane >> 4, q = lane & 15;
    const int n0 = blockIdx.x * 64, m0 = blockIdx.y * 64;
    f32x4 acc[4] = {{0,0,0,0},{0,0,0,0},{0,0,0,0},{0,0,0,0}};

    for (int ch = 0; ch < 8; ++ch) {       // 8 chunks of K=128
        __syncthreads();                   // previous compute done
        for (int i = tid; i < 2048; i += 256) {   // stage A (both planes)
            int pl = i >> 10, rem = i & 1023;
            int r = rem >> 4, cc = rem & 15;
            const __bf16* s = (pl ? xlo : xhi) + (size_t)(m0 + r) * RNN + ch * 128 + cc * 8;
            bf16x8 v = *(const bf16x8*)s;
            *(bf16x8*)&Aim[pl][r >> 4][cc >> 2][(((cc & 3) << 4) + (r & 15)) << 3] = v;
        }
        for (int i = tid; i < 2048; i += 256) {   // stage B (both planes)
            int pl = i >> 10, rem = i & 1023;
            int r = rem >> 4, cc = rem & 15;
            const __bf16* s = Wt + ((size_t)(pl ? 4096 : 0) + n0 + r) * 2048 + ch * 128 + cc * 8;
            bf16x8 v = *(const bf16x8*)s;
            *(bf16x8*)&Bim[pl][r >> 4][cc >> 2][(((cc & 3) << 4) + (r & 15)) << 3] = v;
        }
        __syncthreads();
#pragma unroll
        for (int kc = 0; kc < 4; ++kc) {
            bf16x8 bhf = *(const bf16x8*)&Bim[0][w][kc][lane << 3];
            bf16x8 blf = *(const bf16x8*)&Bim[1][w][kc][lane << 3];
#pragma unroll
            for (int mt = 0; mt < 4; ++mt) {
                bf16x8 ahf = *(const bf16x8*)&Aim[0][mt][kc][lane << 3];
                bf16x8 alf = *(const bf16x8*)&Aim[1][mt][kc][lane << 3];
                acc[mt] = __builtin_amdgcn_mfma_f32_16x16x32_bf16(ahf, bhf, acc[mt], 0, 0, 0);
                acc[mt] = __builtin_amdgcn_mfma_f32_16x16x32_bf16(alf, bhf, acc[mt], 0, 0, 0);
                acc[mt] = __builtin_amdgcn_mfma_f32_16x16x32_bf16(ahf, blf, acc[mt], 0, 0, 0);
            }
        }
    }
    const int n = n0 + w * 16 + q;
    const float bv = bias[n];
#pragma unroll
    for (int mt = 0; mt < 4; ++mt)
#pragma unroll
        for (int r = 0; r < 4; ++r) {
            int m = m0 + mt * 16 + g * 4 + r;
            zx[(size_t)m * 4096 + n] = acc[mt][r] + bv;
        }
}

// ---------------------------------------------------------------------------
// Flat single-level fence-free barriers (sc1 payloads; visibility =
// vmcnt drain + slot store/poll; slots padded 64 B; one slot per block).
__device__ __forceinline__ void bar_all(unsigned* slots, int bk, int tid, unsigned gen) {
    drain_vm();
    __syncthreads();
    if (tid == 0) ast(&slots[bk * AR_STRIDE], gen);
    if (tid < GBLK) {
        while (ald(&slots[tid * AR_STRIDE]) < gen) __builtin_amdgcn_s_sleep(1);
    }
    __syncthreads();
}
__device__ __forceinline__ void bar_gate(unsigned* slots, int bk, bool arrive,
                                         int tid, unsigned gen) {
    drain_vm();
    __syncthreads();
    if (arrive && tid == 0) ast(&slots[bk * AR_STRIDE], gen);
    if (tid < BATCH) {
        while (ald(&slots[tid * AR_STRIDE]) < gen) __builtin_amdgcn_s_sleep(1);
    }
    __syncthreads();
}

// ---------------------------------------------------------------------------
// Persistent per-layer recurrence. 128 blocks x 256 threads, cooperative
// (co-residency only). Wh hi+lo in LDS (lane-read order, conflict-free).
// Wave w -> (mt = w&1, khalf = w>>1): each wave covers BOTH 16-col tiles
// over half of K; h rows read ONCE per block via normal 16B loads from the
// time-indexed xhi/xlo (sc1-written; each address read once per dispatch).
// Partial accs exchanged via LDS; kh0 waves finalize + write z (sc1).
__global__ __launch_bounds__(256, 1) void k_rnn(
        const __bf16* __restrict__ Wl,    // layer base [2][4096][2048]
        const float* __restrict__ zx,     // [SEQ*32][4096] (bias folded)
        float* __restrict__ z,            // [32][4096] scratch (sc1 only)
        __bf16* __restrict__ xhi, __bf16* __restrict__ xlo,  // [SEQ*32][1024]
        const float* __restrict__ g5, const float* __restrict__ b5,
        unsigned* bar, unsigned gen0)
{
    __shared__ __bf16 wl[2][32768];       // 128 KB: Wh hi, lo (lane-read order)
    __shared__ f32x4 pred[2][2][64];      // 4 KB partial accs [mt][nt][lane]
    __shared__ float red[4][8];
    unsigned* bar2 = bar + GBLK * AR_STRIDE;

    const int bk = blockIdx.x, tid = threadIdx.x;
    const int lane = tid & 63, w = tid >> 6;
    const int q = lane & 15, g = lane >> 4;
    const int mt = w & 1, kh = w >> 1;
    const int ncol = (bk << 5) + q;       // nt=0 col; nt=1 at +16
    const int zr0  = (mt << 4) + (g << 2);

    // ---- stage Wh hi+lo into LDS (lane-read order) ----
    {
        const __bf16* hi_src = Wl + ((size_t)(bk << 5)) * 2048 + RNN;
        const __bf16* lo_src = Wl + ((size_t)(4096 + (bk << 5))) * 2048 + RNN;
        for (int i = tid; i < 8192; i += 256) {
            int pl = i >> 12, rem = i & 4095;
            int r = rem >> 7, cc = rem & 127;
            const __bf16* s = (pl ? lo_src : hi_src) + (size_t)r * 2048 + cc * 8;
            bf16x8 v = *(const bf16x8*)s;
            int rnt = r >> 4, rq = r & 15, kc = cc >> 2, rg = cc & 3;
            *(bf16x8*)&wl[pl][((rnt * 32 + kc) << 9) + ((rg * 16 + rq) << 3)] = v;
        }
    }

    // ---- gate-block constants (blocks 0..31) ----
    const bool is_gate = (bk < BATCH);
    f32x4 gi, bi, gj, bj, gf, bfv, go, bo, g4, b4;
    if (is_gate) {
        gi = *(const f32x4*)(g5 + 0*RNN + tid*4); bi = *(const f32x4*)(b5 + 0*RNN + tid*4);
        gj = *(const f32x4*)(g5 + 1*RNN + tid*4); bj = *(const f32x4*)(b5 + 1*RNN + tid*4);
        gf = *(const f32x4*)(g5 + 2*RNN + tid*4); bfv= *(const f32x4*)(b5 + 2*RNN + tid*4);
        go = *(const f32x4*)(g5 + 3*RNN + tid*4); bo = *(const f32x4*)(b5 + 3*RNN + tid*4);
        g4 = *(const f32x4*)(g5 + 4*RNN + tid*4); b4 = *(const f32x4*)(b5 + 4*RNN + tid*4);
    }
    const float inv = 1.f / (float)RNN;
    f32x4 creg = {0.f, 0.f, 0.f, 0.f};    // cell state lives in registers
    __syncthreads();   // LDS staged

    const __bf16* bh0 = &wl[0][0]        + (lane << 3);   // nt=0 hi (+kc<<9)
    const __bf16* bl0 = &wl[1][0]        + (lane << 3);   // nt=0 lo
    const __bf16* bh1 = &wl[0][32 << 9]  + (lane << 3);   // nt=1 hi
    const __bf16* bl1 = &wl[1][32 << 9]  + (lane << 3);   // nt=1 lo

    // zx prefetch (t = 0), kh0 waves only (they finalize z)
    float zv0[4], zv1[4];
    if (kh == 0) {
        const float* zxp = zx + (size_t)zr0 * 4096 + ncol;
#pragma unroll
        for (int r = 0; r < 4; ++r) {
            zv0[r] = zxp[(size_t)r * 4096];
            zv1[r] = zxp[(size_t)r * 4096 + 16];
        }
    }

    for (int t = 0; t < SEQ; ++t) {
        const unsigned gen = gen0 + (unsigned)t + 1u;
        // ---- phase A: z_t = zx[t] + h_{t-1} @ Wh (K-split across waves) ----
        f32x4 a00={0,0,0,0}, a01={0,0,0,0}, a02={0,0,0,0};
        f32x4 a10={0,0,0,0}, a11={0,0,0,0}, a12={0,0,0,0};
        if (t > 0) {
            const __bf16* ah = xhi + ((size_t)(t - 1) * BATCH + (mt << 4) + q) * RNN;
            const __bf16* al = xlo + ((size_t)(t - 1) * BATCH + (mt << 4) + q) * RNN;
            const int k0 = kh << 4;
#pragma unroll 4
            for (int kc = k0; kc < k0 + 16; ++kc) {
                bf16x8 ahf = *(const bf16x8*)(ah + (kc << 5) + (g << 3));   // normal 16B
                bf16x8 alf = *(const bf16x8*)(al + (kc << 5) + (g << 3));
                bf16x8 b0h = *(const bf16x8*)(bh0 + (kc << 9));
                bf16x8 b0l = *(const bf16x8*)(bl0 + (kc << 9));
                bf16x8 b1h = *(const bf16x8*)(bh1 + (kc << 9));
                bf16x8 b1l = *(const bf16x8*)(bl1 + (kc << 9));
                a00 = __builtin_amdgcn_mfma_f32_16x16x32_bf16(ahf, b0h, a00, 0, 0, 0);
                a01 = __builtin_amdgcn_mfma_f32_16x16x32_bf16(alf, b0h, a01, 0, 0, 0);
                a02 = __builtin_amdgcn_mfma_f32_16x16x32_bf16(ahf, b0l, a02, 0, 0, 0);
                a10 = __builtin_amdgcn_mfma_f32_16x16x32_bf16(ahf, b1h, a10, 0, 0, 0);
                a11 = __builtin_amdgcn_mfma_f32_16x16x32_bf16(alf, b1h, a11, 0, 0, 0);
                a12 = __builtin_amdgcn_mfma_f32_16x16x32_bf16(ahf, b1l, a12, 0, 0, 0);
            }
        }
        {
            f32x4 s0, s1;
#pragma unroll
            for (int j = 0; j < 4; ++j) {
                s0[j] = a00[j] + a01[j] + a02[j];
                s1[j] = a10[j] + a11[j] + a12[j];
            }
            if (kh == 1) { pred[mt][0][lane] = s0; pred[mt][1][lane] = s1; }
            __syncthreads();
            if (kh == 0) {
                f32x4 p0 = pred[mt][0][lane], p1 = pred[mt][1][lane];
#pragma unroll
                for (int r = 0; r < 4; ++r) {
                    astf(&z[(size_t)(zr0 + r) * 4096 + ncol],      s0[r] + p0[r] + zv0[r]);
                    astf(&z[(size_t)(zr0 + r) * 4096 + ncol + 16], s1[r] + p1[r] + zv1[r]);
                }
            }
        }
        bar_all(bar, bk, tid, gen);    // z visible

        // ---- prefetch zx for t+1 (constant data; hides under phase B) ----
        if (kh == 0 && t + 1 < SEQ) {
            const float* zxp = zx + ((size_t)(t + 1) * BATCH + zr0) * 4096 + ncol;
#pragma unroll
            for (int r = 0; r < 4; ++r) {
                zv0[r] = zxp[(size_t)r * 4096];
                zv1[r] = zxp[(size_t)r * 4096 + 16];
            }
        }

        // ---- phase B: gates (blocks 0..31), c in registers ----
        if (is_gate) {
            const int b = bk;
            const float* zrow = z + (size_t)b * 4096 + tid * 4;
            auto ld4 = [&](const float* p) -> f32x4 {
                U128F x;
                x.u[0] = ald64((const unsigned long long*)p);
                x.u[1] = ald64((const unsigned long long*)p + 1);
                return x.f;
            };
            f32x4 zi = ld4(zrow), zjv = ld4(zrow + 1024),
                  zfv = ld4(zrow + 2048), zov = ld4(zrow + 3072);
            float s[8];
            s[0] = zi[0]+zi[1]+zi[2]+zi[3];
            s[1] = zi[0]*zi[0]+zi[1]*zi[1]+zi[2]*zi[2]+zi[3]*zi[3];
            s[2] = zjv[0]+zjv[1]+zjv[2]+zjv[3];
            s[3] = zjv[0]*zjv[0]+zjv[1]*zjv[1]+zjv[2]*zjv[2]+zjv[3]*zjv[3];
            s[4] = zfv[0]+zfv[1]+zfv[2]+zfv[3];
            s[5] = zfv[0]*zfv[0]+zfv[1]*zfv[1]+zfv[2]*zfv[2]+zfv[3]*zfv[3];
            s[6] = zov[0]+zov[1]+zov[2]+zov[3];
            s[7] = zov[0]*zov[0]+zov[1]*zov[1]+zov[2]*zov[2]+zov[3]*zov[3];
#pragma unroll
            for (int o = 32; o; o >>= 1)
#pragma unroll
                for (int i = 0; i < 8; ++i) s[i] += __shfl_xor(s[i], o);
            if (lane == 0) {
#pragma unroll
                for (int i = 0; i < 8; ++i) red[w][i] = s[i];
            }
            __syncthreads();
            float tot[8];
#pragma unroll
            for (int i = 0; i < 8; ++i) tot[i] = red[0][i]+red[1][i]+red[2][i]+red[3][i];

            float mi = tot[0]*inv, ri = rsqrtf(tot[1]*inv - mi*mi + 1e-5f);
            float mj = tot[2]*inv, rj = rsqrtf(tot[3]*inv - mj*mj + 1e-5f);
            float mf = tot[4]*inv, rf = rsqrtf(tot[5]*inv - mf*mf + 1e-5f);
            float mo = tot[6]*inv, ro = rsqrtf(tot[7]*inv - mo*mo + 1e-5f);

            f32x4 onrm;
            float cs = 0.f, cq = 0.f;
#pragma unroll
            for (int j = 0; j < 4; ++j) {
                float iv = (zi[j]-mi)*ri*gi[j] + bi[j];
                float jv = (zjv[j]-mj)*rj*gj[j] + bj[j];
                float fv = (zfv[j]-mf)*rf*gf[j] + bfv[j];
                float ov = (zov[j]-mo)*ro*go[j] + bo[j];
                float cc = creg[j] * sigm(fv + 1.0f) + sigm(iv) * tanhf(jv);
                creg[j] = cc; onrm[j] = ov;
                cs += cc; cq += cc*cc;
            }

            __syncthreads();   // protect red[] reuse
            float s2a = cs, s2b = cq;
#pragma unroll
            for (int o = 32; o; o >>= 1) { s2a += __shfl_xor(s2a, o); s2b += __shfl_xor(s2b, o); }
            if (lane == 0) { red[w][0] = s2a; red[w][1] = s2b; }
            __syncthreads();
            float mc = (red[0][0]+red[1][0]+red[2][0]+red[3][0]) * inv;
            float vc = (red[0][1]+red[1][1]+red[2][1]+red[3][1]) * inv - mc*mc;
            float rc = rsqrtf(vc + 1e-5f);

            bf16x4 hh, hl;
#pragma unroll
            for (int j = 0; j < 4; ++j) {
                float cn = (creg[j]-mc)*rc*g4[j] + b4[j];
                float h = tanhf(cn) * sigm(onrm[j]);
                __bf16 a = (__bf16)h;
                hh[j] = a; hl[j] = (__bf16)(h - (float)a);
            }
            U64B ph, pl;
            ph.v = hh; pl.v = hl;
            // single h store: time-indexed x buffers (sc1 -> coherence point)
            ast64((unsigned long long*)&xhi[((size_t)t * BATCH + b) * RNN + tid * 4], ph.u);
            ast64((unsigned long long*)&xlo[((size_t)t * BATCH + b) * RNN + tid * 4], pl.u);
        }
        bar_gate(bar2, bk, is_gate, tid, gen);   // h visible
    }
}

// ---------------------------------------------------------------------------
// logits[m][v] = sum_k h[m][k]*smw[v][k] + smb[v], m = b*128+t; plain bf16,
// LDS-staged (BK=256). Source row in time-major buffer = (m&127)*32+(m>>7).
__global__ __launch_bounds__(256) void k_proj(const __bf16* __restrict__ xs,
                                              const __bf16* __restrict__ wv,
                                              const float* __restrict__ sb,
                                              float* __restrict__ out) {
    __shared__ __bf16 Aim[4][8][512];      // 32 KB
    __shared__ __bf16 Bim[4][8][512];      // 32 KB
    const int tid = threadIdx.x;
    const int lane = tid & 63, w = tid >> 6;
    const int g = lane >> 4, q = lane & 15;
    const int n0 = blockIdx.x * 64, m0 = blockIdx.y * 64;
    f32x4 acc[4] = {{0,0,0,0},{0,0,0,0},{0,0,0,0},{0,0,0,0}};

    for (int ch = 0; ch < 4; ++ch) {       // 4 chunks of K=256
        __syncthreads();
        for (int i = tid; i < 2048; i += 256) {   // stage A
            int r = i >> 5, cc = i & 31;
            int m = m0 + r;
            const __bf16* s = xs + (size_t)((m & 127) * 32 + (m >> 7)) * RNN + ch * 256 + cc * 8;
            bf16x8 v = *(const bf16x8*)s;
            *(bf16x8*)&Aim[r >> 4][cc >> 2][(((cc & 3) << 4) + (r & 15)) << 3] = v;
        }
        for (int i = tid; i < 2048; i += 256) {   // stage B
            int r = i >> 5, cc = i & 31;
            const __bf16* s = wv + (size_t)(n0 + r) * RNN + ch * 256 + cc * 8;
            bf16x8 v = *(const bf16x8*)s;
            *(bf16x8*)&Bim[r >> 4][cc >> 2][(((cc & 3) << 4) + (r & 15)) << 3] = v;
        }
        __syncthreads();
#pragma unroll
        for (int kc = 0; kc < 8; ++kc) {
            bf16x8 bfr = *(const bf16x8*)&Bim[w][kc][lane << 3];
#pragma unroll
            for (int mt = 0; mt < 4; ++mt) {
                bf16x8 afr = *(const bf16x8*)&Aim[mt][kc][lane << 3];
                acc[mt] = __builtin_amdgcn_mfma_f32_16x16x32_bf16(afr, bfr, acc[mt], 0, 0, 0);
            }
        }
    }
    const int n = n0 + w * 16 + q;
    const float bv = sb[n];
#pragma unroll
    for (int mt = 0; mt < 4; ++mt)
#pragma unroll
        for (int r = 0; r < 4; ++r) {
            int m = m0 + mt * 16 + g * 4 + r;
            __builtin_nontemporal_store(acc[mt][r] + bv, &out[(size_t)m * VOCAB + n]);
        }
}

// ---------------------------------------------------------------------------
extern "C" void kernel_launch(void* const* d_in, const int* in_sizes, int n_in,
                              void* d_out, int out_size, void* d_ws, size_t ws_size,
                              hipStream_t stream) {
    const int*   input = (const int*)  d_in[0];
    const float* emb   = (const float*)d_in[1];
    const float* W     = (const float*)d_in[2];
    const float* bias  = (const float*)d_in[3];
    const float* ln_g  = (const float*)d_in[4];
    const float* ln_b  = (const float*)d_in[5];
    const float* smw   = (const float*)d_in[6];
    const float* smb   = (const float*)d_in[7];
    float* out = (float*)d_out;

    char* p = (char*)d_ws;
    auto alloc = [&](size_t bytes) { char* r = p; p += (bytes + 255) & ~(size_t)255; return r; };
    __bf16* Wt   = (__bf16*)alloc((size_t)NLAY * 2 * 4096 * 2048 * 2); // 134.2 MB
    __bf16* smwb = (__bf16*)alloc((size_t)VOCAB * RNN * 2);            // 65.5 MB
    __bf16* xhi  = (__bf16*)alloc((size_t)SEQ * BATCH * RNN * 2);      // 8.4 MB
    __bf16* xlo  = (__bf16*)alloc((size_t)SEQ * BATCH * RNN * 2);      // 8.4 MB
    float*  zx   = (float*) alloc((size_t)SEQ * BATCH * 4096 * 4);     // 67.1 MB
    float*  z    = (float*) alloc((size_t)BATCH * 4096 * 4);           // 512 KB
    unsigned* bar= (unsigned*)alloc(2 * GBLK * AR_STRIDE * 4);         // 2 slot arrays

    hipMemsetAsync(bar, 0, 2 * GBLK * AR_STRIDE * 4, stream);

    k_cvt_w<<<dim3(64, 32, NLAY), 256, 0, stream>>>(W, Wt);
    k_cvt<<<(VOCAB * RNN) / (8 * 256), 256, 0, stream>>>(smw, smwb);
    k_embed<<<SEQ * BATCH, 256, 0, stream>>>(input, emb, xhi, xlo);

    for (int l = 0; l < NLAY; ++l) {
        const __bf16* Wl  = Wt + (size_t)l * 2 * 4096 * 2048;
        const float*  bl  = bias + (size_t)l * 4096;
        const float*  gl  = ln_g + (size_t)l * 5 * RNN;
        const float*  bbl = ln_b + (size_t)l * 5 * RNN;
        k_xgemm<<<dim3(64, 64), 256, 0, stream>>>(xhi, xlo, Wl, bl, zx);
        {
            const __bf16* Wl_ = Wl;
            const float*  zx_ = zx;
            float* z_ = z;
            __bf16 *xhi_ = xhi, *xlo_ = xlo;
            const float *gl_ = gl, *bbl_ = bbl;
            unsigned* bar_ = bar;
            unsigned gen0 = (unsigned)(l * SEQ);
            void* args[] = {(void*)&Wl_, (void*)&zx_, (void*)&z_,
                            (void*)&xhi_, (void*)&xlo_, (void*)&gl_, (void*)&bbl_,
                            (void*)&bar_, (void*)&gen0};
            hipLaunchCooperativeKernel((const void*)k_rnn,
                                       dim3(GBLK), dim3(256), args, 0, stream);
        }
    }
    // final layer output (bf16 hi) lives in xhi (time-major)
    k_proj<<<dim3(VOCAB / 64, 4096 / 64), 256, 0, stream>>>(xhi, smwb, smb, out);
}